// Round 1
// baseline (1357.306 us; speedup 1.0000x reference)
//
#include <hip/hip_runtime.h>
#include <math.h>

#define SEQ    2048
#define DMODEL 1024
#define NH     16
#define DH     64
#define NB     2
#define BHN    (NB*NH)

static constexpr float SCALE = 0.02209708691207961f; // 1/sqrt(2048)

__device__ __forceinline__ void mm4x4(const float4 a, const float4 b, float acc[4][4]) {
    acc[0][0] += a.x*b.x; acc[0][1] += a.x*b.y; acc[0][2] += a.x*b.z; acc[0][3] += a.x*b.w;
    acc[1][0] += a.y*b.x; acc[1][1] += a.y*b.y; acc[1][2] += a.y*b.z; acc[1][3] += a.y*b.w;
    acc[2][0] += a.z*b.x; acc[2][1] += a.z*b.y; acc[2][2] += a.z*b.z; acc[2][3] += a.z*b.w;
    acc[3][0] += a.w*b.x; acc[3][1] += a.w*b.y; acc[3][2] += a.w*b.z; acc[3][3] += a.w*b.w;
}

// ---------------- Q/K/V projection: Y[b,h,s,e] = sum_d X[b,s,d] * W[h,d,e] ----------------
// grid: (SEQ/64, 1, 3*BHN), block 256. which = z / BHN selects Q/K/V.
__global__ __launch_bounds__(256) void proj_kernel(
    const float* __restrict__ queries, const float* __restrict__ keys, const float* __restrict__ values,
    const float* __restrict__ WQ, const float* __restrict__ WK, const float* __restrict__ WV,
    float* __restrict__ Qg, float* __restrict__ Kg, float* __restrict__ Vg)
{
    const int z = blockIdx.z;
    const int which = z / BHN;
    const int bh = z % BHN;
    const int b = bh / NH, h = bh % NH;
    const float* X = (which == 0) ? queries : (which == 1) ? keys : values;
    const float* W = (which == 0) ? WQ : (which == 1) ? WK : WV;
    float* Y = (which == 0) ? Qg : (which == 1) ? Kg : Vg;
    const int s0 = blockIdx.x * 64;

    __shared__ float Xs[16][68];   // [d][s] transposed
    __shared__ float Ws[16][68];   // [d][e]
    const int t = threadIdx.x;
    const int tx = t & 15, ty = t >> 4;
    const int xs = t >> 2, xd = (t & 3) * 4;   // X tile load coords (64 s x 16 d)
    const int wd = t >> 4, we = (t & 15) * 4;  // W tile load coords (16 d x 64 e)

    float acc[4][4] = {};
    const float* Xbase = X + ((size_t)b * SEQ + s0) * DMODEL;
    const float* Wbase = W + (size_t)h * DMODEL * DH;

    for (int k0 = 0; k0 < DMODEL; k0 += 16) {
        float4 xv = *(const float4*)(Xbase + (size_t)xs * DMODEL + k0 + xd);
        float4 wv = *(const float4*)(Wbase + (size_t)(k0 + wd) * DH + we);
        Xs[xd+0][xs] = xv.x; Xs[xd+1][xs] = xv.y; Xs[xd+2][xs] = xv.z; Xs[xd+3][xs] = xv.w;
        *(float4*)&Ws[wd][we] = wv;
        __syncthreads();
        #pragma unroll
        for (int kk = 0; kk < 16; ++kk) {
            float4 a  = *(const float4*)&Xs[kk][ty*4];
            float4 bv = *(const float4*)&Ws[kk][tx*4];
            mm4x4(a, bv, acc);
        }
        __syncthreads();
    }
    float* Ybase = Y + ((size_t)bh * SEQ + s0) * DH;
    #pragma unroll
    for (int i = 0; i < 4; ++i) {
        float4 o = make_float4(acc[i][0], acc[i][1], acc[i][2], acc[i][3]);
        *(float4*)(Ybase + (size_t)(ty*4 + i) * DH + tx*4) = o;
    }
}

// ---------------- Pass 1: per-column (key) softmax stats over query axis ----------------
// grid: (SEQ/64 k-tiles, BHN), block 256.
__global__ __launch_bounds__(256) void stats_kernel(
    const float* __restrict__ Qg, const float* __restrict__ Kg,
    float* __restrict__ Mg, float* __restrict__ Dg, const int* __restrict__ mask_p)
{
    const int bh = blockIdx.y;
    const int k0 = blockIdx.x * 64;
    const int masking = mask_p[0];

    __shared__ float Ks[64][68];   // [d][k]
    __shared__ float Qs[64][68];   // [d][q]
    __shared__ float red[16][64];
    __shared__ float m_run[64];
    __shared__ float d_run[64];

    const int t = threadIdx.x;
    const int tx = t & 15, ty = t >> 4;
    const int r0 = t >> 4, c4 = (t & 15) * 4;

    // load K tile transposed
    const float* Kbase = Kg + ((size_t)bh * SEQ + k0) * DH;
    #pragma unroll
    for (int i = 0; i < 4; ++i) {
        int row = r0 + i * 16;
        float4 v = *(const float4*)(Kbase + (size_t)row * DH + c4);
        Ks[c4+0][row] = v.x; Ks[c4+1][row] = v.y; Ks[c4+2][row] = v.z; Ks[c4+3][row] = v.w;
    }
    if (t < 64) { m_run[t] = -INFINITY; d_run[t] = 0.f; }
    __syncthreads();

    const int q_start = masking ? k0 : 0;
    for (int q0 = q_start; q0 < SEQ; q0 += 64) {
        // load Q tile transposed
        const float* Qbase = Qg + ((size_t)bh * SEQ + q0) * DH;
        #pragma unroll
        for (int i = 0; i < 4; ++i) {
            int row = r0 + i * 16;
            float4 v = *(const float4*)(Qbase + (size_t)row * DH + c4);
            Qs[c4+0][row] = v.x; Qs[c4+1][row] = v.y; Qs[c4+2][row] = v.z; Qs[c4+3][row] = v.w;
        }
        __syncthreads();

        float y[4][4] = {};
        #pragma unroll 8
        for (int d = 0; d < 64; ++d) {
            float4 a  = *(const float4*)&Qs[d][ty*4];   // 4 q rows
            float4 bv = *(const float4*)&Ks[d][tx*4];   // 4 k cols
            mm4x4(a, bv, y);
        }
        // bias + scale + mask
        #pragma unroll
        for (int i = 0; i < 4; ++i) {
            int q = q0 + ty*4 + i;
            #pragma unroll
            for (int j = 0; j < 4; ++j) {
                int k = k0 + tx*4 + j;
                float v = y[i][j] + ((k <= q) ? (float)(k - q) : 0.f);
                v *= SCALE;
                if (masking && (k > q)) v = -INFINITY;
                y[i][j] = v;
            }
        }
        // per-thread column max -> reduce across ty
        #pragma unroll
        for (int j = 0; j < 4; ++j) {
            float lm = fmaxf(fmaxf(y[0][j], y[1][j]), fmaxf(y[2][j], y[3][j]));
            red[ty][tx*4 + j] = lm;
        }
        __syncthreads();
        if (t < 64) {
            float tm = red[0][t];
            #pragma unroll
            for (int r = 1; r < 16; ++r) tm = fmaxf(tm, red[r][t]);
            float mo = m_run[t];
            float mn = fmaxf(mo, tm);
            m_run[t] = mn;
            d_run[t] = d_run[t] * __expf(mo - mn);
        }
        __syncthreads();
        #pragma unroll
        for (int j = 0; j < 4; ++j) {
            float mc = m_run[tx*4 + j];
            float ps = __expf(y[0][j] - mc) + __expf(y[1][j] - mc)
                     + __expf(y[2][j] - mc) + __expf(y[3][j] - mc);
            red[ty][tx*4 + j] = ps;
        }
        __syncthreads();
        if (t < 64) {
            float s = 0.f;
            #pragma unroll
            for (int r = 0; r < 16; ++r) s += red[r][t];
            d_run[t] += s;
        }
        __syncthreads();
    }
    if (t < 64) {
        Mg[(size_t)bh * SEQ + k0 + t] = m_run[t];
        Dg[(size_t)bh * SEQ + k0 + t] = d_run[t];
    }
}

// ---------------- Pass 2: out[q,e] = sum_k exp(y[q,k]-m[k])/D[k] * V[k,e] ----------------
// grid: (SEQ/64 q-tiles, BHN), block 256. Writes attn as [B, S, H*DH].
__global__ __launch_bounds__(256) void attn_out_kernel(
    const float* __restrict__ Qg, const float* __restrict__ Kg, const float* __restrict__ Vg,
    const float* __restrict__ Mg, const float* __restrict__ Dg,
    float* __restrict__ attn, const int* __restrict__ mask_p)
{
    const int bh = blockIdx.y;
    const int b = bh / NH, h = bh % NH;
    const int q0 = blockIdx.x * 64;
    const int masking = mask_p[0];

    __shared__ float Qs[64][68];   // [d][q]
    __shared__ float Ks[64][68];   // [d][k]
    __shared__ float Vs[64][64];   // [k][e]
    __shared__ float Ss[64][68];   // [q][k] weights
    __shared__ float mcol[64];
    __shared__ float rD[64];

    const int t = threadIdx.x;
    const int tx = t & 15, ty = t >> 4;
    const int r0 = t >> 4, c4 = (t & 15) * 4;

    // load Q tile transposed (fixed for the block)
    const float* Qbase = Qg + ((size_t)bh * SEQ + q0) * DH;
    #pragma unroll
    for (int i = 0; i < 4; ++i) {
        int row = r0 + i * 16;
        float4 v = *(const float4*)(Qbase + (size_t)row * DH + c4);
        Qs[c4+0][row] = v.x; Qs[c4+1][row] = v.y; Qs[c4+2][row] = v.z; Qs[c4+3][row] = v.w;
    }

    float acc[4][4] = {};
    const int ktmax = masking ? (q0 / 64) : (SEQ / 64 - 1);
    for (int kt = 0; kt <= ktmax; ++kt) {
        const int k0 = kt * 64;
        const float* Kbase = Kg + ((size_t)bh * SEQ + k0) * DH;
        const float* Vbase = Vg + ((size_t)bh * SEQ + k0) * DH;
        __syncthreads();   // previous iteration's reads of Ks/Vs/Ss done (also covers Q load)
        #pragma unroll
        for (int i = 0; i < 4; ++i) {
            int row = r0 + i * 16;
            float4 v = *(const float4*)(Kbase + (size_t)row * DH + c4);
            Ks[c4+0][row] = v.x; Ks[c4+1][row] = v.y; Ks[c4+2][row] = v.z; Ks[c4+3][row] = v.w;
            *(float4*)&Vs[row][c4] = *(const float4*)(Vbase + (size_t)row * DH + c4);
        }
        if (t < 64) {
            mcol[t] = Mg[(size_t)bh * SEQ + k0 + t];
            rD[t]   = 1.f / Dg[(size_t)bh * SEQ + k0 + t];
        }
        __syncthreads();

        // scores
        float y[4][4] = {};
        #pragma unroll 8
        for (int d = 0; d < 64; ++d) {
            float4 a  = *(const float4*)&Qs[d][ty*4];
            float4 bv = *(const float4*)&Ks[d][tx*4];
            mm4x4(a, bv, y);
        }
        #pragma unroll
        for (int i = 0; i < 4; ++i) {
            int q = q0 + ty*4 + i;
            float w[4];
            #pragma unroll
            for (int j = 0; j < 4; ++j) {
                int k = k0 + tx*4 + j;
                float v = (y[i][j] + ((k <= q) ? (float)(k - q) : 0.f)) * SCALE;
                bool valid = (!masking) || (k <= q);
                int kl = tx*4 + j;
                w[j] = valid ? (__expf(v - mcol[kl]) * rD[kl]) : 0.f;
            }
            *(float4*)&Ss[ty*4 + i][tx*4] = make_float4(w[0], w[1], w[2], w[3]);
        }
        __syncthreads();

        // PV: acc[q][e] += Ss[q][kk] * Vs[kk][e]
        #pragma unroll 8
        for (int kk = 0; kk < 64; ++kk) {
            float4 bv = *(const float4*)&Vs[kk][tx*4];
            float a0 = Ss[ty*4+0][kk], a1 = Ss[ty*4+1][kk], a2 = Ss[ty*4+2][kk], a3 = Ss[ty*4+3][kk];
            acc[0][0] += a0*bv.x; acc[0][1] += a0*bv.y; acc[0][2] += a0*bv.z; acc[0][3] += a0*bv.w;
            acc[1][0] += a1*bv.x; acc[1][1] += a1*bv.y; acc[1][2] += a1*bv.z; acc[1][3] += a1*bv.w;
            acc[2][0] += a2*bv.x; acc[2][1] += a2*bv.y; acc[2][2] += a2*bv.z; acc[2][3] += a2*bv.w;
            acc[3][0] += a3*bv.x; acc[3][1] += a3*bv.y; acc[3][2] += a3*bv.z; acc[3][3] += a3*bv.w;
        }
    }
    // write attn tile: [B, S, H*DH]
    float* obase = attn + ((size_t)(b * SEQ + q0)) * DMODEL + h * DH;
    #pragma unroll
    for (int i = 0; i < 4; ++i) {
        float4 o = make_float4(acc[i][0], acc[i][1], acc[i][2], acc[i][3]);
        *(float4*)(obase + (size_t)(ty*4 + i) * DMODEL + tx*4) = o;
    }
}

// ---------------- Final: out = attn[4096,1024] @ WO[1024,1024] ----------------
// grid: (DMODEL/64, NB*SEQ/64), block 256.
__global__ __launch_bounds__(256) void final_gemm(
    const float* __restrict__ A, const float* __restrict__ Bm, float* __restrict__ C)
{
    const int n0 = blockIdx.x * 64;
    const int m0 = blockIdx.y * 64;
    __shared__ float As[16][68];   // [k][m]
    __shared__ float Bs[16][68];   // [k][n]
    const int t = threadIdx.x;
    const int tx = t & 15, ty = t >> 4;
    const int am = t >> 2, ad = (t & 3) * 4;
    const int bd = t >> 4, bn = (t & 15) * 4;

    float acc[4][4] = {};
    for (int k0 = 0; k0 < DMODEL; k0 += 16) {
        float4 av = *(const float4*)(A + (size_t)(m0 + am) * DMODEL + k0 + ad);
        float4 bv = *(const float4*)(Bm + (size_t)(k0 + bd) * DMODEL + n0 + bn);
        As[ad+0][am] = av.x; As[ad+1][am] = av.y; As[ad+2][am] = av.z; As[ad+3][am] = av.w;
        *(float4*)&Bs[bd][bn] = bv;
        __syncthreads();
        #pragma unroll
        for (int kk = 0; kk < 16; ++kk) {
            float4 a = *(const float4*)&As[kk][ty*4];
            float4 b = *(const float4*)&Bs[kk][tx*4];
            mm4x4(a, b, acc);
        }
        __syncthreads();
    }
    #pragma unroll
    for (int i = 0; i < 4; ++i) {
        float4 o = make_float4(acc[i][0], acc[i][1], acc[i][2], acc[i][3]);
        *(float4*)(C + (size_t)(m0 + ty*4 + i) * DMODEL + n0 + tx*4) = o;
    }
}

extern "C" void kernel_launch(void* const* d_in, const int* in_sizes, int n_in,
                              void* d_out, int out_size, void* d_ws, size_t ws_size,
                              hipStream_t stream) {
    const float* keys    = (const float*)d_in[0];
    const float* queries = (const float*)d_in[1];
    const float* values  = (const float*)d_in[2];
    const float* WQ      = (const float*)d_in[3];
    const float* WK      = (const float*)d_in[4];
    const float* WV      = (const float*)d_in[5];
    const float* WO      = (const float*)d_in[6];
    const int*   mask_p  = (const int*)d_in[7];
    float* out = (float*)d_out;

    const size_t n_qkv = (size_t)NB * NH * SEQ * DH;     // 4,194,304
    const size_t n_md  = (size_t)NB * NH * SEQ;          // 65,536
    float* ws = (float*)d_ws;
    float* Qg   = ws;
    float* Kg   = Qg + n_qkv;
    float* Vg   = Kg + n_qkv;
    float* attn = Vg + n_qkv;
    float* Mg   = attn + (size_t)NB * SEQ * DMODEL;
    float* Dg   = Mg + n_md;

    proj_kernel<<<dim3(SEQ/64, 1, 3*BHN), dim3(256), 0, stream>>>(
        queries, keys, values, WQ, WK, WV, Qg, Kg, Vg);
    stats_kernel<<<dim3(SEQ/64, BHN), dim3(256), 0, stream>>>(
        Qg, Kg, Mg, Dg, mask_p);
    attn_out_kernel<<<dim3(SEQ/64, BHN), dim3(256), 0, stream>>>(
        Qg, Kg, Vg, Mg, Dg, attn, mask_p);
    final_gemm<<<dim3(DMODEL/64, (NB*SEQ)/64), dim3(256), 0, stream>>>(
        attn, WO, out);
}

// Round 3
// 357.558 us; speedup vs baseline: 3.7960x; 3.7960x over previous
//
#include <hip/hip_runtime.h>
#include <math.h>

#define SEQ    2048
#define DMODEL 1024
#define NH     16
#define DH     64
#define NB     2
#define BHN    (NB*NH)

static constexpr float SCALE = 0.02209708691207961f; // 1/sqrt(2048)

typedef __attribute__((ext_vector_type(8))) short short8;
typedef __attribute__((ext_vector_type(4))) short short4v;
typedef __attribute__((ext_vector_type(4))) float f32x4;

__device__ __forceinline__ short f2bf(float f) {
    union { float f; unsigned u; } v; v.f = f;
    unsigned r = (v.u + 0x7FFFu + ((v.u >> 16) & 1u)) >> 16;
    return (short)r;
}

__device__ __forceinline__ void load16_lds(const short* g, short* l) {
    __builtin_amdgcn_global_load_lds(
        (const __attribute__((address_space(1))) unsigned int*)g,
        (__attribute__((address_space(3))) unsigned int*)l,
        16, 0, 0);
}

// Stage a 64x64 bf16 tile (row stride 64 elements, contiguous) into LDS with
// XOR-8-block swizzle: LDS[row][b] = G[row][b ^ (row&7)] (blocks of 8 elements).
__device__ __forceinline__ void stage_tile64(const short* g, short* s, int t) {
    int wave = t >> 6, lane = t & 63;
    #pragma unroll
    for (int i = 0; i < 2; ++i) {
        int E   = i * 2048 + wave * 512 + lane * 8;
        int row = E >> 6;
        int blk = (lane & 7) ^ (row & 7);
        load16_lds(g + row * 64 + blk * 8, s + i * 2048 + wave * 512);
    }
}

// Stage a 128x64 bf16 tile from a matrix with row stride ldg.
__device__ __forceinline__ void stage_tile128(const short* g, short* s, int t, int ldg) {
    int wave = t >> 6, lane = t & 63;
    #pragma unroll
    for (int i = 0; i < 4; ++i) {
        int E   = i * 2048 + wave * 512 + lane * 8;
        int row = E >> 6;
        int blk = (lane & 7) ^ (row & 7);
        load16_lds(g + (size_t)row * ldg + blk * 8, s + i * 2048 + wave * 512);
    }
}

// Read an MFMA A/B fragment from a swizzled [rows][64] LDS tile.
// lane: m/n = lane&15 (+rowbase), k = (lane>>4)*8 + j + ks*32
__device__ __forceinline__ short8 frag_sw(const short* s, int rowbase, int ks, int lane) {
    int m   = rowbase + (lane & 15);
    int q   = lane >> 4;
    int blk = (ks * 4 + q) ^ (m & 7);
    return *(const short8*)(s + m * 64 + blk * 8);
}

// Read a fragment from an unswizzled stride-72 LDS tile.
__device__ __forceinline__ short8 frag72(const short* s, int rowbase, int ks, int lane) {
    int m = rowbase + (lane & 15);
    int q = lane >> 4;
    return *(const short8*)(s + m * 72 + ks * 32 + q * 8);
}

// ---------------- converters ----------------
__global__ __launch_bounds__(256) void convert_x(
    const float* __restrict__ q, const float* __restrict__ k, const float* __restrict__ v,
    short* __restrict__ Xq, short* __restrict__ Xk, short* __restrict__ Xv)
{
    const int z = blockIdx.z;
    const float* src = (z == 0) ? q : (z == 1) ? k : v;
    short* dst = (z == 0) ? Xq : (z == 1) ? Xk : Xv;
    size_t idx = ((size_t)blockIdx.x * 256 + threadIdx.x) * 8;
    float4 a = *(const float4*)(src + idx);
    float4 b = *(const float4*)(src + idx + 4);
    short8 o;
    o[0] = f2bf(a.x); o[1] = f2bf(a.y); o[2] = f2bf(a.z); o[3] = f2bf(a.w);
    o[4] = f2bf(b.x); o[5] = f2bf(b.y); o[6] = f2bf(b.z); o[7] = f2bf(b.w);
    *(short8*)(dst + idx) = o;
}

// W[h][k][e] (z<3) or WO[k][n] (z==3)  ->  Wt[n][k] bf16 (n = h*64+e)
__global__ __launch_bounds__(256) void convert_w(
    const float* __restrict__ WQ, const float* __restrict__ WK,
    const float* __restrict__ WV, const float* __restrict__ WO,
    short* __restrict__ WQt, short* __restrict__ WKt,
    short* __restrict__ WVt, short* __restrict__ WOt)
{
    const int z = blockIdx.z;
    const int k0 = blockIdx.x * 64;
    const int ny = blockIdx.y;            // n-tile = head for z<3
    const float* W = (z == 0) ? WQ : (z == 1) ? WK : (z == 2) ? WV : WO;
    short* Wt = (z == 0) ? WQt : (z == 1) ? WKt : (z == 2) ? WVt : WOt;

    __shared__ float Ts[64][68];          // [n-local][k-local]
    const int t = threadIdx.x;
    const int tr = t >> 4, tc4 = (t & 15) * 4;

    #pragma unroll
    for (int i = 0; i < 4; ++i) {
        int row = tr + i * 16;            // k-local
        float4 v;
        if (z < 3) v = *(const float4*)(W + (size_t)ny * DMODEL * DH + (size_t)(k0 + row) * DH + tc4);
        else       v = *(const float4*)(W + (size_t)(k0 + row) * DMODEL + ny * 64 + tc4);
        Ts[tc4 + 0][row] = v.x; Ts[tc4 + 1][row] = v.y;
        Ts[tc4 + 2][row] = v.z; Ts[tc4 + 3][row] = v.w;
    }
    __syncthreads();
    #pragma unroll
    for (int i = 0; i < 4; ++i) {
        int nl = tr + i * 16;
        short4v o;
        o[0] = f2bf(Ts[nl][tc4 + 0]); o[1] = f2bf(Ts[nl][tc4 + 1]);
        o[2] = f2bf(Ts[nl][tc4 + 2]); o[3] = f2bf(Ts[nl][tc4 + 3]);
        *(short4v*)(Wt + (size_t)(ny * 64 + nl) * DMODEL + k0 + tc4) = o;
    }
}

// ---------------- NT-GEMM: C[m][n] = sum_k A[m][k] * Bt[n][k] ----------------
// M=4096, N=1024, K=1024. Tile 128x128, BK=64. 4 waves, 64x64 each.
// phase 0: z in 0..2 selects (Xq,WQt)->Qg scatter / (Xk,WKt)->Kg / (Xv,WVt)->Vg
// phase 1: (attnb, WOt) -> fp32 out, row-major
__global__ __launch_bounds__(256) void gemm_nt(
    const short* __restrict__ A0, const short* __restrict__ A1, const short* __restrict__ A2,
    const short* __restrict__ B0, const short* __restrict__ B1, const short* __restrict__ B2,
    short* __restrict__ Y0, short* __restrict__ Y1, short* __restrict__ Y2,
    float* __restrict__ outF, int phase)
{
    const int z = blockIdx.z;
    const short* A  = (phase == 1) ? A0 : (z == 0) ? A0 : (z == 1) ? A1 : A2;
    const short* Bt = (phase == 1) ? B0 : (z == 0) ? B0 : (z == 1) ? B1 : B2;
    short* Y        = (z == 0) ? Y0 : (z == 1) ? Y1 : Y2;

    const int n0 = blockIdx.x * 128;
    const int m0 = blockIdx.y * 128;

    __shared__ short As[128 * 64];
    __shared__ short Bs[128 * 64];

    const int t = threadIdx.x;
    const int wave = t >> 6, lane = t & 63;
    const int wrow = (wave >> 1) * 64, wcol = (wave & 1) * 64;

    f32x4 acc[4][4];
    #pragma unroll
    for (int i = 0; i < 4; ++i)
        #pragma unroll
        for (int j = 0; j < 4; ++j)
            acc[i][j] = (f32x4)0.f;

    for (int k0 = 0; k0 < DMODEL; k0 += 64) {
        __syncthreads();
        stage_tile128(A + (size_t)m0 * DMODEL + k0, As, t, DMODEL);
        stage_tile128(Bt + (size_t)n0 * DMODEL + k0, Bs, t, DMODEL);
        __syncthreads();
        #pragma unroll
        for (int ks = 0; ks < 2; ++ks) {
            short8 af[4], bf[4];
            #pragma unroll
            for (int mt = 0; mt < 4; ++mt) af[mt] = frag_sw(As, wrow + mt * 16, ks, lane);
            #pragma unroll
            for (int nt = 0; nt < 4; ++nt) bf[nt] = frag_sw(Bs, wcol + nt * 16, ks, lane);
            #pragma unroll
            for (int mt = 0; mt < 4; ++mt)
                #pragma unroll
                for (int nt = 0; nt < 4; ++nt)
                    acc[mt][nt] = __builtin_amdgcn_mfma_f32_16x16x32_bf16(
                        af[mt], bf[nt], acc[mt][nt], 0, 0, 0);
        }
    }

    // epilogue: C layout col = lane&15, row = (lane>>4)*4 + i
    #pragma unroll
    for (int mt = 0; mt < 4; ++mt) {
        #pragma unroll
        for (int nt = 0; nt < 4; ++nt) {
            #pragma unroll
            for (int i = 0; i < 4; ++i) {
                int m = m0 + wrow + mt * 16 + (lane >> 4) * 4 + i;
                int n = n0 + wcol + nt * 16 + (lane & 15);
                float val = acc[mt][nt][i];
                if (phase == 1) {
                    outF[(size_t)m * 1024 + n] = val;
                } else {
                    int b = m >> 11, s = m & 2047, h = n >> 6, e = n & 63;
                    Y[((size_t)(b * NH + h) * SEQ + s) * DH + e] = f2bf(val);
                }
            }
        }
    }
}

// ---------------- stats: per-key-column max/sum over query axis ----------------
// grid (32 ktiles, 32 bh). D[kcol][q] = K . Q^T via MFMA (A=K, B=Q).
__global__ __launch_bounds__(256) void stats_mfma(
    const short* __restrict__ Qg, const short* __restrict__ Kg,
    float* __restrict__ Mg, float* __restrict__ Dg, const int* __restrict__ mask_p)
{
    const int bh = blockIdx.y;
    const int k0 = blockIdx.x * 64;
    const int masking = mask_p[0];

    __shared__ short Ks[64 * 64];
    __shared__ short Qs[64 * 64];

    const int t = threadIdx.x;
    const int wave = t >> 6, lane = t & 63;

    stage_tile64(Kg + ((size_t)bh * SEQ + k0) * DH, Ks, t);

    float m_run[4], d_run[4];
    #pragma unroll
    for (int i = 0; i < 4; ++i) { m_run[i] = -INFINITY; d_run[i] = 0.f; }

    const int q0s = masking ? k0 : 0;
    for (int q0 = q0s; q0 < SEQ; q0 += 64) {
        __syncthreads();
        stage_tile64(Qg + ((size_t)bh * SEQ + q0) * DH, Qs, t);
        __syncthreads();

        f32x4 acc[4];
        #pragma unroll
        for (int nt = 0; nt < 4; ++nt) acc[nt] = (f32x4)0.f;
        #pragma unroll
        for (int ks = 0; ks < 2; ++ks) {
            short8 a = frag_sw(Ks, wave * 16, ks, lane);
            #pragma unroll
            for (int nt = 0; nt < 4; ++nt)
                acc[nt] = __builtin_amdgcn_mfma_f32_16x16x32_bf16(
                    a, frag_sw(Qs, nt * 16, ks, lane), acc[nt], 0, 0, 0);
        }

        const int kc = k0 + wave * 16 + (lane >> 4) * 4;
        #pragma unroll
        for (int i = 0; i < 4; ++i) {
            float vv[4]; float tm = -INFINITY;
            #pragma unroll
            for (int nt = 0; nt < 4; ++nt) {
                int q = q0 + nt * 16 + (lane & 15);
                int k = kc + i;
                float v = (acc[nt][i] + ((k <= q) ? (float)(k - q) : 0.f)) * SCALE;
                if (masking && (k > q)) v = -INFINITY;
                vv[nt] = v;
                tm = fmaxf(tm, v);
            }
            #pragma unroll
            for (int mm = 1; mm < 16; mm <<= 1) tm = fmaxf(tm, __shfl_xor(tm, mm));
            float nm = fmaxf(m_run[i], tm);
            float es = 0.f;
            #pragma unroll
            for (int nt = 0; nt < 4; ++nt) es += __expf(vv[nt] - nm);
            #pragma unroll
            for (int mm = 1; mm < 16; mm <<= 1) es += __shfl_xor(es, mm);
            d_run[i] = d_run[i] * __expf(m_run[i] - nm) + es;
            m_run[i] = nm;
        }
    }

    if ((lane & 15) == 0) {
        #pragma unroll
        for (int i = 0; i < 4; ++i) {
            int idx = k0 + wave * 16 + (lane >> 4) * 4 + i;
            Mg[(size_t)bh * SEQ + idx] = m_run[i];
            Dg[(size_t)bh * SEQ + idx] = d_run[i];
        }
    }
}

// ---------------- attn_out: O[q][e] = sum_k P[q][k] V[k][e] ----------------
// grid (32 qtiles, 32 bh). Scores via MFMA (A=Q,B=K), P through LDS bf16, PV via MFMA.
__global__ __launch_bounds__(256) void attn_mfma(
    const short* __restrict__ Qg, const short* __restrict__ Kg, const short* __restrict__ Vg,
    const float* __restrict__ Mg, const float* __restrict__ Dg,
    short* __restrict__ attnb, const int* __restrict__ mask_p)
{
    const int bh = blockIdx.y;
    const int b = bh / NH, h = bh % NH;
    const int q0 = blockIdx.x * 64;
    const int masking = mask_p[0];

    __shared__ short Qs[64 * 64];
    __shared__ short Ks[64 * 64];
    __shared__ short Vt[64 * 72];   // V^T: [e][k]
    __shared__ short Ps[64 * 72];   // P:   [q][k]
    __shared__ float mcol[64];
    __shared__ float rDl[64];

    const int t = threadIdx.x;
    const int wave = t >> 6, lane = t & 63;

    stage_tile64(Qg + ((size_t)bh * SEQ + q0) * DH, Qs, t);

    f32x4 oacc[4];
    #pragma unroll
    for (int nt = 0; nt < 4; ++nt) oacc[nt] = (f32x4)0.f;

    const int ktmax = masking ? (q0 / 64) : (SEQ / 64 - 1);
    for (int kt = 0; kt <= ktmax; ++kt) {
        const int k0 = kt * 64;
        __syncthreads();
        stage_tile64(Kg + ((size_t)bh * SEQ + k0) * DH, Ks, t);
        // V transpose into LDS: Vt[e][k]
        {
            int r = t & 63, eb = (t >> 6) * 16;
            const short* vsrc = Vg + ((size_t)bh * SEQ + k0 + r) * DH + eb;
            short8 v0 = *(const short8*)(vsrc);
            short8 v1 = *(const short8*)(vsrc + 8);
            #pragma unroll
            for (int j = 0; j < 8; ++j) Vt[(eb + j) * 72 + r] = v0[j];
            #pragma unroll
            for (int j = 0; j < 8; ++j) Vt[(eb + 8 + j) * 72 + r] = v1[j];
        }
        if (t < 64) {
            mcol[t] = Mg[(size_t)bh * SEQ + k0 + t];
            rDl[t]  = 1.f / Dg[(size_t)bh * SEQ + k0 + t];
        }
        __syncthreads();

        // scores: D[q][kcol]
        f32x4 sacc[4];
        #pragma unroll
        for (int nt = 0; nt < 4; ++nt) sacc[nt] = (f32x4)0.f;
        #pragma unroll
        for (int ks = 0; ks < 2; ++ks) {
            short8 a = frag_sw(Qs, wave * 16, ks, lane);
            #pragma unroll
            for (int nt = 0; nt < 4; ++nt)
                sacc[nt] = __builtin_amdgcn_mfma_f32_16x16x32_bf16(
                    a, frag_sw(Ks, nt * 16, ks, lane), sacc[nt], 0, 0, 0);
        }
        // P = exp((s+bias)*scale - m[k]) / D[k], bf16 into LDS
        #pragma unroll
        for (int nt = 0; nt < 4; ++nt) {
            int kl = nt * 16 + (lane & 15);
            int k = k0 + kl;
            float mc = mcol[kl], rd = rDl[kl];
            #pragma unroll
            for (int i = 0; i < 4; ++i) {
                int qrow = wave * 16 + (lane >> 4) * 4 + i;
                int q = q0 + qrow;
                float v = (sacc[nt][i] + ((k <= q) ? (float)(k - q) : 0.f)) * SCALE;
                float p = (masking && (k > q)) ? 0.f : __expf(v - mc) * rd;
                Ps[qrow * 72 + kl] = f2bf(p);
            }
        }
        __syncthreads();

        // PV: O[q][e] += P[q][k] * Vt[e][k]^T
        #pragma unroll
        for (int ks = 0; ks < 2; ++ks) {
            short8 a = frag72(Ps, wave * 16, ks, lane);
            #pragma unroll
            for (int nt = 0; nt < 4; ++nt)
                oacc[nt] = __builtin_amdgcn_mfma_f32_16x16x32_bf16(
                    a, frag72(Vt, nt * 16, ks, lane), oacc[nt], 0, 0, 0);
        }
    }

    // epilogue: attnb[b][q][h*64+e] bf16
    #pragma unroll
    for (int nt = 0; nt < 4; ++nt) {
        #pragma unroll
        for (int i = 0; i < 4; ++i) {
            int q = q0 + wave * 16 + (lane >> 4) * 4 + i;
            int e = nt * 16 + (lane & 15);
            attnb[((size_t)(b * SEQ + q)) * DMODEL + h * DH + e] = f2bf(oacc[nt][i]);
        }
    }
}

extern "C" void kernel_launch(void* const* d_in, const int* in_sizes, int n_in,
                              void* d_out, int out_size, void* d_ws, size_t ws_size,
                              hipStream_t stream) {
    const float* keys    = (const float*)d_in[0];
    const float* queries = (const float*)d_in[1];
    const float* values  = (const float*)d_in[2];
    const float* WQ      = (const float*)d_in[3];
    const float* WK      = (const float*)d_in[4];
    const float* WV      = (const float*)d_in[5];
    const float* WO      = (const float*)d_in[6];
    const int*   mask_p  = (const int*)d_in[7];
    float* out = (float*)d_out;

    const size_t nX = (size_t)NB * SEQ * DMODEL;   // 4,194,304
    const size_t nW = (size_t)DMODEL * DMODEL;     // 1,048,576
    const size_t nQ = (size_t)BHN * SEQ * DH;      // 4,194,304
    const size_t nM = (size_t)BHN * SEQ;           // 65,536

    short* ws = (short*)d_ws;
    short* Xq    = ws;            // bf16 queries
    short* Xk    = Xq + nX;
    short* Xv    = Xk + nX;
    short* WQt   = Xv + nX;       // [n][k] packed transposed weights
    short* WKt   = WQt + nW;
    short* WVt   = WKt + nW;
    short* WOt   = WVt + nW;
    short* Qg    = WOt + nW;      // [bh][s][64] bf16
    short* Kg    = Qg + nQ;
    short* Vg    = Kg + nQ;
    short* attnb = Vg + nQ;       // [b][s][1024] bf16
    float* Mg    = (float*)(attnb + nX);
    float* Dg    = Mg + nM;

    convert_x<<<dim3(2048, 1, 3), dim3(256), 0, stream>>>(queries, keys, values, Xq, Xk, Xv);
    convert_w<<<dim3(16, 16, 4), dim3(256), 0, stream>>>(WQ, WK, WV, WO, WQt, WKt, WVt, WOt);
    gemm_nt<<<dim3(8, 32, 3), dim3(256), 0, stream>>>(
        Xq, Xk, Xv, WQt, WKt, WVt, Qg, Kg, Vg, nullptr, 0);
    stats_mfma<<<dim3(32, 32), dim3(256), 0, stream>>>(Qg, Kg, Mg, Dg, mask_p);
    attn_mfma<<<dim3(32, 32), dim3(256), 0, stream>>>(Qg, Kg, Vg, Mg, Dg, attnb, mask_p);
    // NOTE: argument order is (A0,A1,A2, B0,B1,B2, Y0,Y1,Y2, outF, phase) —
    // WOt must land in the B0 slot (round-2 crash was WOt in A1 → Bt=nullptr).
    gemm_nt<<<dim3(8, 32, 1), dim3(256), 0, stream>>>(
        attnb, nullptr, nullptr, WOt, nullptr, nullptr, nullptr, nullptr, nullptr, out, 1);
}

// Round 4
// 306.857 us; speedup vs baseline: 4.4233x; 1.1652x over previous
//
#include <hip/hip_runtime.h>
#include <math.h>

#define SEQ    2048
#define DMODEL 1024
#define NH     16
#define DH     64
#define NB     2
#define BHN    (NB*NH)

static constexpr float SCALE = 0.02209708691207961f; // 1/sqrt(2048)

typedef __attribute__((ext_vector_type(8))) short short8;
typedef __attribute__((ext_vector_type(4))) short short4v;
typedef __attribute__((ext_vector_type(4))) float f32x4;

__device__ __forceinline__ short f2bf(float f) {
    union { float f; unsigned u; } v; v.f = f;
    unsigned r = (v.u + 0x7FFFu + ((v.u >> 16) & 1u)) >> 16;
    return (short)r;
}

__device__ __forceinline__ void load16_lds(const short* g, short* l) {
    __builtin_amdgcn_global_load_lds(
        (const __attribute__((address_space(1))) unsigned int*)g,
        (__attribute__((address_space(3))) unsigned int*)l,
        16, 0, 0);
}

// Stage nIter*32 rows of a [rows][64] bf16 tile (row stride ldg) into LDS with
// XOR-8-block swizzle: LDS[row][b] = G[row][b ^ (row&7)] (blocks of 8 elements).
__device__ __forceinline__ void stage_rows(const short* g, short* s, int t, int ldg, int nIter) {
    int wave = t >> 6, lane = t & 63;
    #pragma unroll
    for (int i = 0; i < 4; ++i) {
        if (i >= nIter) break;
        int E   = i * 2048 + wave * 512 + lane * 8;
        int row = E >> 6;
        int blk = (lane & 7) ^ (row & 7);
        load16_lds(g + (size_t)row * ldg + blk * 8, s + i * 2048 + wave * 512);
    }
}

// Read an MFMA A/B fragment from a swizzled [rows][64] LDS tile.
// lane: m/n = rowbase + (lane&15), k = (lane>>4)*8 + j + ks*32
__device__ __forceinline__ short8 frag_sw(const short* s, int rowbase, int ks, int lane) {
    int m   = rowbase + (lane & 15);
    int q   = lane >> 4;
    int blk = (ks * 4 + q) ^ (m & 7);
    return *(const short8*)(s + m * 64 + blk * 8);
}

// Read a fragment from an unswizzled stride-72 LDS tile.
__device__ __forceinline__ short8 frag72(const short* s, int rowbase, int ks, int lane) {
    int m = rowbase + (lane & 15);
    int q = lane >> 4;
    return *(const short8*)(s + m * 72 + ks * 32 + q * 8);
}

// ---------------- converters ----------------
__global__ __launch_bounds__(256) void convert_x(
    const float* __restrict__ q, const float* __restrict__ k, const float* __restrict__ v,
    short* __restrict__ Xq, short* __restrict__ Xk, short* __restrict__ Xv)
{
    const int z = blockIdx.z;
    const float* src = (z == 0) ? q : (z == 1) ? k : v;
    short* dst = (z == 0) ? Xq : (z == 1) ? Xk : Xv;
    size_t idx = ((size_t)blockIdx.x * 256 + threadIdx.x) * 8;
    float4 a = *(const float4*)(src + idx);
    float4 b = *(const float4*)(src + idx + 4);
    short8 o;
    o[0] = f2bf(a.x); o[1] = f2bf(a.y); o[2] = f2bf(a.z); o[3] = f2bf(a.w);
    o[4] = f2bf(b.x); o[5] = f2bf(b.y); o[6] = f2bf(b.z); o[7] = f2bf(b.w);
    *(short8*)(dst + idx) = o;
}

// W[h][k][e] (z<3) or WO[k][n] (z==3)  ->  Wt[n][k] bf16 (n = h*64+e)
__global__ __launch_bounds__(256) void convert_w(
    const float* __restrict__ WQ, const float* __restrict__ WK,
    const float* __restrict__ WV, const float* __restrict__ WO,
    short* __restrict__ WQt, short* __restrict__ WKt,
    short* __restrict__ WVt, short* __restrict__ WOt)
{
    const int z = blockIdx.z;
    const int k0 = blockIdx.x * 64;
    const int ny = blockIdx.y;            // n-tile = head for z<3
    const float* W = (z == 0) ? WQ : (z == 1) ? WK : (z == 2) ? WV : WO;
    short* Wt = (z == 0) ? WQt : (z == 1) ? WKt : (z == 2) ? WVt : WOt;

    __shared__ float Ts[64][68];          // [n-local][k-local]
    const int t = threadIdx.x;
    const int tr = t >> 4, tc4 = (t & 15) * 4;

    #pragma unroll
    for (int i = 0; i < 4; ++i) {
        int row = tr + i * 16;            // k-local
        float4 v;
        if (z < 3) v = *(const float4*)(W + (size_t)ny * DMODEL * DH + (size_t)(k0 + row) * DH + tc4);
        else       v = *(const float4*)(W + (size_t)(k0 + row) * DMODEL + ny * 64 + tc4);
        Ts[tc4 + 0][row] = v.x; Ts[tc4 + 1][row] = v.y;
        Ts[tc4 + 2][row] = v.z; Ts[tc4 + 3][row] = v.w;
    }
    __syncthreads();
    #pragma unroll
    for (int i = 0; i < 4; ++i) {
        int nl = tr + i * 16;
        short4v o;
        o[0] = f2bf(Ts[nl][tc4 + 0]); o[1] = f2bf(Ts[nl][tc4 + 1]);
        o[2] = f2bf(Ts[nl][tc4 + 2]); o[3] = f2bf(Ts[nl][tc4 + 3]);
        *(short4v*)(Wt + (size_t)(ny * 64 + nl) * DMODEL + k0 + tc4) = o;
    }
}

// ---------------- NT-GEMM: C = X[m][k] * Wt[n][k]^T ----------------
// M=4096, N=1024, K=1024. Tile 128x128, BK=64. 4 waves, 64x64 each.
// phase 0, z in {0,1}: D[n][m] orientation -> Y[bh][s][e], packed-e stores
// phase 0, z == 2:     D[m][n] orientation -> Vt[bh][e][s], packed-s stores
// phase 1:             D[n][m] orientation -> fp32 out[m][n], float4 stores
__global__ __launch_bounds__(256) void gemm_nt(
    const short* __restrict__ A0, const short* __restrict__ A1, const short* __restrict__ A2,
    const short* __restrict__ B0, const short* __restrict__ B1, const short* __restrict__ B2,
    short* __restrict__ Y0, short* __restrict__ Y1, short* __restrict__ Y2,
    float* __restrict__ outF, int phase)
{
    const int z = blockIdx.z;
    const short* X  = (phase == 1) ? A0 : (z == 0) ? A0 : (z == 1) ? A1 : A2;
    const short* Wt = (phase == 1) ? B0 : (z == 0) ? B0 : (z == 1) ? B1 : B2;
    short* Y        = (z == 0) ? Y0 : (z == 1) ? Y1 : Y2;
    const bool vOrient = (phase == 0) && (z == 2);

    const int n0 = blockIdx.x * 128;
    const int m0 = blockIdx.y * 128;

    __shared__ short As[128 * 64];   // X rows (m)
    __shared__ short Bs[128 * 64];   // Wt rows (n)

    const int t = threadIdx.x;
    const int wave = t >> 6, lane = t & 63;
    const int wrow = (wave >> 1) * 64, wcol = (wave & 1) * 64;
    const int quad = lane >> 4, l15 = lane & 15;

    f32x4 acc[4][4];
    #pragma unroll
    for (int i = 0; i < 4; ++i)
        #pragma unroll
        for (int j = 0; j < 4; ++j)
            acc[i][j] = (f32x4)0.f;

    for (int k0 = 0; k0 < DMODEL; k0 += 64) {
        __syncthreads();
        stage_rows(X  + (size_t)m0 * DMODEL + k0, As, t, DMODEL, 4);
        stage_rows(Wt + (size_t)n0 * DMODEL + k0, Bs, t, DMODEL, 4);
        __syncthreads();
        if (!vOrient) {
            // acc[nt][mt] = D[n][m]
            #pragma unroll
            for (int ks = 0; ks < 2; ++ks) {
                short8 xf[4], wf[4];
                #pragma unroll
                for (int i = 0; i < 4; ++i) xf[i] = frag_sw(As, wrow + i * 16, ks, lane);
                #pragma unroll
                for (int i = 0; i < 4; ++i) wf[i] = frag_sw(Bs, wcol + i * 16, ks, lane);
                #pragma unroll
                for (int a = 0; a < 4; ++a)
                    #pragma unroll
                    for (int b = 0; b < 4; ++b)
                        acc[a][b] = __builtin_amdgcn_mfma_f32_16x16x32_bf16(
                            wf[a], xf[b], acc[a][b], 0, 0, 0);
            }
        } else {
            // acc[mt][nt] = D[m][n]
            #pragma unroll
            for (int ks = 0; ks < 2; ++ks) {
                short8 xf[4], wf[4];
                #pragma unroll
                for (int i = 0; i < 4; ++i) xf[i] = frag_sw(As, wrow + i * 16, ks, lane);
                #pragma unroll
                for (int i = 0; i < 4; ++i) wf[i] = frag_sw(Bs, wcol + i * 16, ks, lane);
                #pragma unroll
                for (int a = 0; a < 4; ++a)
                    #pragma unroll
                    for (int b = 0; b < 4; ++b)
                        acc[a][b] = __builtin_amdgcn_mfma_f32_16x16x32_bf16(
                            xf[a], wf[b], acc[a][b], 0, 0, 0);
            }
        }
    }

    if (vOrient) {
        // D[m][n]: rows m = s (4 consecutive over reg idx), col n = (h,e)
        #pragma unroll
        for (int a = 0; a < 4; ++a) {
            #pragma unroll
            for (int b = 0; b < 4; ++b) {
                int m = m0 + wrow + a * 16 + quad * 4;      // s base (4 consecutive)
                int n = n0 + wcol + b * 16 + l15;            // (h,e)
                int bb = m >> 11, s = m & 2047, h = n >> 6, e = n & 63;
                short4v o;
                #pragma unroll
                for (int i = 0; i < 4; ++i) o[i] = f2bf(acc[a][b][i]);
                // Vt[bh][e][s]
                *(short4v*)(Y + ((size_t)((bb * NH + h) * DH + e)) * SEQ + s) = o;
            }
        }
    } else if (phase == 1) {
        // D[n][m]: rows n (4 consecutive), col m; out[m][n] fp32
        #pragma unroll
        for (int a = 0; a < 4; ++a) {
            #pragma unroll
            for (int b = 0; b < 4; ++b) {
                int n = n0 + wcol + a * 16 + quad * 4;       // 4 consecutive n
                int m = m0 + wrow + b * 16 + l15;
                float4 o = make_float4(acc[a][b][0], acc[a][b][1], acc[a][b][2], acc[a][b][3]);
                *(float4*)(outF + (size_t)m * DMODEL + n) = o;
            }
        }
    } else {
        // D[n][m]: rows n = (h,e) (4 consecutive e), col m = (b,s); Y[bh][s][e]
        #pragma unroll
        for (int a = 0; a < 4; ++a) {
            #pragma unroll
            for (int b = 0; b < 4; ++b) {
                int n = n0 + wcol + a * 16 + quad * 4;       // 4 consecutive e
                int m = m0 + wrow + b * 16 + l15;
                int bb = m >> 11, s = m & 2047, h = n >> 6, e = n & 63;
                short4v o;
                #pragma unroll
                for (int i = 0; i < 4; ++i) o[i] = f2bf(acc[a][b][i]);
                *(short4v*)(Y + ((size_t)((bb * NH + h) * SEQ + s)) * DH + e) = o;
            }
        }
    }
}

// ---------------- stats: rD[k] = 1 / sum_q exp(y[q][k]) (no max needed) ----------------
// grid (32 ktiles, 32 bh). S^T[k][q] via MFMA (A=K, B=Q). Per-lane register
// accumulation across the whole q loop; one shfl reduction at the end.
// Safe without max: y = (QK + bias)*0.0221, bias <= 0, |QK*scale| <~ 1.5.
__global__ __launch_bounds__(256) void stats_mfma(
    const short* __restrict__ Qg, const short* __restrict__ Kg,
    float* __restrict__ rDg, const int* __restrict__ mask_p)
{
    const int bh = blockIdx.y;
    const int k0 = blockIdx.x * 64;
    const int masking = mask_p[0];

    __shared__ short Ks[64 * 64];
    __shared__ short Qs[64 * 64];

    const int t = threadIdx.x;
    const int wave = t >> 6, lane = t & 63;
    const int quad = lane >> 4, l15 = lane & 15;

    stage_rows(Kg + ((size_t)bh * SEQ + k0) * DH, Ks, t, DH, 2);

    float dsum[4] = {0.f, 0.f, 0.f, 0.f};
    const int kc = k0 + wave * 16 + quad * 4;

    const int q0s = masking ? k0 : 0;
    for (int q0 = q0s; q0 < SEQ; q0 += 64) {
        __syncthreads();
        stage_rows(Qg + ((size_t)bh * SEQ + q0) * DH, Qs, t, DH, 2);
        __syncthreads();

        f32x4 acc[4];
        #pragma unroll
        for (int nt = 0; nt < 4; ++nt) acc[nt] = (f32x4)0.f;
        #pragma unroll
        for (int ks = 0; ks < 2; ++ks) {
            short8 a = frag_sw(Ks, wave * 16, ks, lane);
            #pragma unroll
            for (int nt = 0; nt < 4; ++nt)
                acc[nt] = __builtin_amdgcn_mfma_f32_16x16x32_bf16(
                    a, frag_sw(Qs, nt * 16, ks, lane), acc[nt], 0, 0, 0);
        }
        // D[k][q]: row k = kc + i, col q = q0 + nt*16 + l15
        #pragma unroll
        for (int nt = 0; nt < 4; ++nt) {
            int q = q0 + nt * 16 + l15;
            #pragma unroll
            for (int i = 0; i < 4; ++i) {
                int k = kc + i;
                float v = (acc[nt][i] + ((k <= q) ? (float)(k - q) : 0.f)) * SCALE;
                float e = __expf(v);
                dsum[i] += (masking && (k > q)) ? 0.f : e;
            }
        }
    }

    // reduce over the 16 q-lanes in each quad-group
    #pragma unroll
    for (int i = 0; i < 4; ++i) {
        float d = dsum[i];
        #pragma unroll
        for (int mm = 1; mm < 16; mm <<= 1) d += __shfl_xor(d, mm);
        dsum[i] = d;
    }
    if (l15 == 0) {
        float4 o = make_float4(1.f / dsum[0], 1.f / dsum[1], 1.f / dsum[2], 1.f / dsum[3]);
        *(float4*)(rDg + (size_t)bh * SEQ + kc) = o;
    }
}

// ---------------- attn: O^T[e][q] = Vt[e][k] . P[q][k] ----------------
// grid (32 qtiles heavy-first, 32 bh). Scores via MFMA (A=Q,B=K), P through
// LDS bf16, PV via MFMA with A=Vt (pre-transposed in global), B=P.
__global__ __launch_bounds__(256) void attn_mfma(
    const short* __restrict__ Qg, const short* __restrict__ Kg, const short* __restrict__ Vt,
    const float* __restrict__ rDg,
    short* __restrict__ attnb, const int* __restrict__ mask_p)
{
    const int bh = blockIdx.y;
    const int b = bh / NH, h = bh % NH;
    const int qt = (SEQ / 64 - 1) - blockIdx.x;   // heavy-first under causal skew
    const int q0 = qt * 64;
    const int masking = mask_p[0];

    __shared__ short Qs[64 * 64];
    __shared__ short Ks[64 * 64];
    __shared__ short Vts[64 * 64];  // Vt tile: rows e, cols k (swizzled)
    __shared__ short Ps[64 * 72];   // P: [q][k]
    __shared__ float rDl[64];

    const int t = threadIdx.x;
    const int wave = t >> 6, lane = t & 63;
    const int quad = lane >> 4, l15 = lane & 15;

    stage_rows(Qg + ((size_t)bh * SEQ + q0) * DH, Qs, t, DH, 2);

    f32x4 oacc[4];
    #pragma unroll
    for (int mt = 0; mt < 4; ++mt) oacc[mt] = (f32x4)0.f;

    const int ktmax = masking ? qt : (SEQ / 64 - 1);
    for (int kt = 0; kt <= ktmax; ++kt) {
        const int k0 = kt * 64;
        __syncthreads();   // previous iteration's reads of Ks/Vts/Ps done (also covers Q stage)
        stage_rows(Kg + ((size_t)bh * SEQ + k0) * DH, Ks, t, DH, 2);
        stage_rows(Vt + ((size_t)bh * DH) * SEQ + k0, Vts, t, SEQ, 2);
        if (t < 64) rDl[t] = rDg[(size_t)bh * SEQ + k0 + t];
        __syncthreads();

        // scores: D[q][k]
        f32x4 sacc[4];
        #pragma unroll
        for (int nt = 0; nt < 4; ++nt) sacc[nt] = (f32x4)0.f;
        #pragma unroll
        for (int ks = 0; ks < 2; ++ks) {
            short8 a = frag_sw(Qs, wave * 16, ks, lane);
            #pragma unroll
            for (int nt = 0; nt < 4; ++nt)
                sacc[nt] = __builtin_amdgcn_mfma_f32_16x16x32_bf16(
                    a, frag_sw(Ks, nt * 16, ks, lane), sacc[nt], 0, 0, 0);
        }
        // P = exp((s+bias)*scale) * rD[k], bf16 into LDS [q][k]
        #pragma unroll
        for (int nt = 0; nt < 4; ++nt) {
            int kl = nt * 16 + l15;
            int k = k0 + kl;
            float rd = rDl[kl];
            #pragma unroll
            for (int i = 0; i < 4; ++i) {
                int qrow = wave * 16 + quad * 4 + i;
                int q = q0 + qrow;
                float v = (sacc[nt][i] + ((k <= q) ? (float)(k - q) : 0.f)) * SCALE;
                float p = (masking && (k > q)) ? 0.f : __expf(v) * rd;
                Ps[qrow * 72 + kl] = f2bf(p);
            }
        }
        __syncthreads();

        // PV: O^T[e][q] += Vt[e][k] * P[q][k]
        #pragma unroll
        for (int ks = 0; ks < 2; ++ks) {
            short8 pb = frag72(Ps, wave * 16, ks, lane);   // B: n=q rows
            #pragma unroll
            for (int mt = 0; mt < 4; ++mt)
                oacc[mt] = __builtin_amdgcn_mfma_f32_16x16x32_bf16(
                    frag_sw(Vts, mt * 16, ks, lane), pb, oacc[mt], 0, 0, 0);
        }
    }

    // epilogue: D[e][q] -> attnb[b][q][h*64+e], 4 consecutive e packed (8 B)
    #pragma unroll
    for (int mt = 0; mt < 4; ++mt) {
        int e = mt * 16 + quad * 4;
        int q = q0 + wave * 16 + l15;
        short4v o;
        #pragma unroll
        for (int i = 0; i < 4; ++i) o[i] = f2bf(oacc[mt][i]);
        *(short4v*)(attnb + ((size_t)(b * SEQ + q)) * DMODEL + h * DH + e) = o;
    }
}

extern "C" void kernel_launch(void* const* d_in, const int* in_sizes, int n_in,
                              void* d_out, int out_size, void* d_ws, size_t ws_size,
                              hipStream_t stream) {
    const float* keys    = (const float*)d_in[0];
    const float* queries = (const float*)d_in[1];
    const float* values  = (const float*)d_in[2];
    const float* WQ      = (const float*)d_in[3];
    const float* WK      = (const float*)d_in[4];
    const float* WV      = (const float*)d_in[5];
    const float* WO      = (const float*)d_in[6];
    const int*   mask_p  = (const int*)d_in[7];
    float* out = (float*)d_out;

    const size_t nX = (size_t)NB * SEQ * DMODEL;   // 4,194,304
    const size_t nW = (size_t)DMODEL * DMODEL;     // 1,048,576
    const size_t nQ = (size_t)BHN * SEQ * DH;      // 4,194,304
    const size_t nM = (size_t)BHN * SEQ;           // 65,536

    short* ws = (short*)d_ws;
    short* Xq    = ws;            // bf16 queries
    short* Xk    = Xq + nX;
    short* Xv    = Xk + nX;
    short* WQt   = Xv + nX;       // [n][k] packed transposed weights
    short* WKt   = WQt + nW;
    short* WVt   = WKt + nW;
    short* WOt   = WVt + nW;
    short* Qg    = WOt + nW;      // [bh][s][64] bf16
    short* Kg    = Qg + nQ;
    short* Vtg   = Kg + nQ;       // [bh][e][s] bf16 (pre-transposed V)
    short* attnb = Vtg + nQ;      // [b][s][1024] bf16
    float* rDg   = (float*)(attnb + nX);

    convert_x<<<dim3(2048, 1, 3), dim3(256), 0, stream>>>(queries, keys, values, Xq, Xk, Xv);
    convert_w<<<dim3(16, 16, 4), dim3(256), 0, stream>>>(WQ, WK, WV, WO, WQt, WKt, WVt, WOt);
    gemm_nt<<<dim3(8, 32, 3), dim3(256), 0, stream>>>(
        Xq, Xk, Xv, WQt, WKt, WVt, Qg, Kg, Vtg, nullptr, 0);
    stats_mfma<<<dim3(32, 32), dim3(256), 0, stream>>>(Qg, Kg, rDg, mask_p);
    attn_mfma<<<dim3(32, 32), dim3(256), 0, stream>>>(Qg, Kg, Vtg, rDg, attnb, mask_p);
    // argument order: (A0,A1,A2, B0,B1,B2, Y0,Y1,Y2, outF, phase) — WOt in B0.
    gemm_nt<<<dim3(8, 32, 1), dim3(256), 0, stream>>>(
        attnb, nullptr, nullptr, WOt, nullptr, nullptr, nullptr, nullptr, nullptr, out, 1);
}

// Round 6
// 299.709 us; speedup vs baseline: 4.5287x; 1.0238x over previous
//
#include <hip/hip_runtime.h>
#include <math.h>

#define SEQ    2048
#define DMODEL 1024
#define NH     16
#define DH     64
#define NB     2
#define BHN    (NB*NH)

static constexpr float SCALE = 0.02209708691207961f; // 1/sqrt(2048)

typedef __attribute__((ext_vector_type(8))) short short8;
typedef __attribute__((ext_vector_type(4))) short short4v;
typedef __attribute__((ext_vector_type(4))) float f32x4;

__device__ __forceinline__ short f2bf(float f) {
    union { float f; unsigned u; } v; v.f = f;
    unsigned r = (v.u + 0x7FFFu + ((v.u >> 16) & 1u)) >> 16;
    return (short)r;
}

// pack two floats to bf16x2 (round-half-up): low16 = a, high16 = b
__device__ __forceinline__ unsigned pack_bf2(float a, float b) {
    union { float f; unsigned u; } ua, ub; ua.f = a; ub.f = b;
    return __builtin_amdgcn_perm(ub.u + 0x8000u, ua.u + 0x8000u, 0x07060302u);
}

__device__ __forceinline__ float bf2f(short s) {
    union { unsigned u; float f; } v; v.u = ((unsigned)(unsigned short)s) << 16;
    return v.f;
}

__device__ __forceinline__ void load16_lds(const short* g, short* l) {
    __builtin_amdgcn_global_load_lds(
        (const __attribute__((address_space(1))) unsigned int*)g,
        (__attribute__((address_space(3))) unsigned int*)l,
        16, 0, 0);
}

// Stage nIter*32 rows of a [rows][64] bf16 tile (row stride ldg) into LDS with
// XOR-8-block swizzle: LDS[row][b] = G[row][b ^ (row&7)] (blocks of 8 elements).
__device__ __forceinline__ void stage_rows(const short* g, short* s, int t, int ldg, int nIter) {
    int wave = t >> 6, lane = t & 63;
    #pragma unroll
    for (int i = 0; i < 4; ++i) {
        if (i >= nIter) break;
        int E   = i * 2048 + wave * 512 + lane * 8;
        int row = E >> 6;
        int blk = (lane & 7) ^ (row & 7);
        load16_lds(g + (size_t)row * ldg + blk * 8, s + i * 2048 + wave * 512);
    }
}

// Read an MFMA A/B fragment from a swizzled [rows][64] LDS tile.
// lane: m/n = rowbase + (lane&15), k = (lane>>4)*8 + j + ks*32
__device__ __forceinline__ short8 frag_sw(const short* s, int rowbase, int ks, int lane) {
    int m   = rowbase + (lane & 15);
    int q   = lane >> 4;
    int blk = (ks * 4 + q) ^ (m & 7);
    return *(const short8*)(s + m * 64 + blk * 8);
}

// ---------------- converters ----------------
__global__ __launch_bounds__(256) void convert_x(
    const float* __restrict__ q, const float* __restrict__ k, const float* __restrict__ v,
    short* __restrict__ Xq, short* __restrict__ Xk, short* __restrict__ Xv)
{
    const int z = blockIdx.z;
    const float* src = (z == 0) ? q : (z == 1) ? k : v;
    short* dst = (z == 0) ? Xq : (z == 1) ? Xk : Xv;
    size_t idx = ((size_t)blockIdx.x * 256 + threadIdx.x) * 8;
    float4 a = *(const float4*)(src + idx);
    float4 b = *(const float4*)(src + idx + 4);
    short8 o;
    o[0] = f2bf(a.x); o[1] = f2bf(a.y); o[2] = f2bf(a.z); o[3] = f2bf(a.w);
    o[4] = f2bf(b.x); o[5] = f2bf(b.y); o[6] = f2bf(b.z); o[7] = f2bf(b.w);
    *(short8*)(dst + idx) = o;
}

// W[h][k][e] (z<3) or WO[k][n] (z==3)  ->  Wt[n][k] bf16 (n = h*64+e)
__global__ __launch_bounds__(256) void convert_w(
    const float* __restrict__ WQ, const float* __restrict__ WK,
    const float* __restrict__ WV, const float* __restrict__ WO,
    short* __restrict__ WQt, short* __restrict__ WKt,
    short* __restrict__ WVt, short* __restrict__ WOt)
{
    const int z = blockIdx.z;
    const int k0 = blockIdx.x * 64;
    const int ny = blockIdx.y;            // n-tile = head for z<3
    const float* W = (z == 0) ? WQ : (z == 1) ? WK : (z == 2) ? WV : WO;
    short* Wt = (z == 0) ? WQt : (z == 1) ? WKt : (z == 2) ? WVt : WOt;

    __shared__ float Ts[64][68];          // [n-local][k-local]
    const int t = threadIdx.x;
    const int tr = t >> 4, tc4 = (t & 15) * 4;

    #pragma unroll
    for (int i = 0; i < 4; ++i) {
        int row = tr + i * 16;            // k-local
        float4 v;
        if (z < 3) v = *(const float4*)(W + (size_t)ny * DMODEL * DH + (size_t)(k0 + row) * DH + tc4);
        else       v = *(const float4*)(W + (size_t)(k0 + row) * DMODEL + ny * 64 + tc4);
        Ts[tc4 + 0][row] = v.x; Ts[tc4 + 1][row] = v.y;
        Ts[tc4 + 2][row] = v.z; Ts[tc4 + 3][row] = v.w;
    }
    __syncthreads();
    #pragma unroll
    for (int i = 0; i < 4; ++i) {
        int nl = tr + i * 16;
        short4v o;
        o[0] = f2bf(Ts[nl][tc4 + 0]); o[1] = f2bf(Ts[nl][tc4 + 1]);
        o[2] = f2bf(Ts[nl][tc4 + 2]); o[3] = f2bf(Ts[nl][tc4 + 3]);
        *(short4v*)(Wt + (size_t)(ny * 64 + nl) * DMODEL + k0 + tc4) = o;
    }
}

// ---------------- NT-GEMM: C = X[m][k] * Wt[n][k]^T ----------------
__global__ __launch_bounds__(256) void gemm_nt(
    const short* __restrict__ A0, const short* __restrict__ A1, const short* __restrict__ A2,
    const short* __restrict__ B0, const short* __restrict__ B1, const short* __restrict__ B2,
    short* __restrict__ Y0, short* __restrict__ Y1, short* __restrict__ Y2,
    float* __restrict__ outF, int phase)
{
    const int z = blockIdx.z;
    const short* X  = (phase == 1) ? A0 : (z == 0) ? A0 : (z == 1) ? A1 : A2;
    const short* Wt = (phase == 1) ? B0 : (z == 0) ? B0 : (z == 1) ? B1 : B2;
    short* Y        = (z == 0) ? Y0 : (z == 1) ? Y1 : Y2;
    const bool vOrient = (phase == 0) && (z == 2);

    const int n0 = blockIdx.x * 128;
    const int m0 = blockIdx.y * 128;

    __shared__ short As[128 * 64];
    __shared__ short Bs[128 * 64];

    const int t = threadIdx.x;
    const int wave = t >> 6, lane = t & 63;
    const int wrow = (wave >> 1) * 64, wcol = (wave & 1) * 64;
    const int quad = lane >> 4, l15 = lane & 15;

    f32x4 acc[4][4];
    #pragma unroll
    for (int i = 0; i < 4; ++i)
        #pragma unroll
        for (int j = 0; j < 4; ++j)
            acc[i][j] = (f32x4)0.f;

    for (int k0 = 0; k0 < DMODEL; k0 += 64) {
        __syncthreads();
        stage_rows(X  + (size_t)m0 * DMODEL + k0, As, t, DMODEL, 4);
        stage_rows(Wt + (size_t)n0 * DMODEL + k0, Bs, t, DMODEL, 4);
        __syncthreads();
        if (!vOrient) {
            #pragma unroll
            for (int ks = 0; ks < 2; ++ks) {
                short8 xf[4], wf[4];
                #pragma unroll
                for (int i = 0; i < 4; ++i) xf[i] = frag_sw(As, wrow + i * 16, ks, lane);
                #pragma unroll
                for (int i = 0; i < 4; ++i) wf[i] = frag_sw(Bs, wcol + i * 16, ks, lane);
                #pragma unroll
                for (int a = 0; a < 4; ++a)
                    #pragma unroll
                    for (int b = 0; b < 4; ++b)
                        acc[a][b] = __builtin_amdgcn_mfma_f32_16x16x32_bf16(
                            wf[a], xf[b], acc[a][b], 0, 0, 0);
            }
        } else {
            #pragma unroll
            for (int ks = 0; ks < 2; ++ks) {
                short8 xf[4], wf[4];
                #pragma unroll
                for (int i = 0; i < 4; ++i) xf[i] = frag_sw(As, wrow + i * 16, ks, lane);
                #pragma unroll
                for (int i = 0; i < 4; ++i) wf[i] = frag_sw(Bs, wcol + i * 16, ks, lane);
                #pragma unroll
                for (int a = 0; a < 4; ++a)
                    #pragma unroll
                    for (int b = 0; b < 4; ++b)
                        acc[a][b] = __builtin_amdgcn_mfma_f32_16x16x32_bf16(
                            xf[a], wf[b], acc[a][b], 0, 0, 0);
            }
        }
    }

    if (vOrient) {
        // D[m][n]: rows m = s (4 consecutive), col n = (h,e) -> Vt[bh][e][s]
        #pragma unroll
        for (int a = 0; a < 4; ++a) {
            #pragma unroll
            for (int b = 0; b < 4; ++b) {
                int m = m0 + wrow + a * 16 + quad * 4;
                int n = n0 + wcol + b * 16 + l15;
                int bb = m >> 11, s = m & 2047, h = n >> 6, e = n & 63;
                short4v o;
                #pragma unroll
                for (int i = 0; i < 4; ++i) o[i] = f2bf(acc[a][b][i]);
                *(short4v*)(Y + ((size_t)((bb * NH + h) * DH + e)) * SEQ + s) = o;
            }
        }
    } else if (phase == 1) {
        #pragma unroll
        for (int a = 0; a < 4; ++a) {
            #pragma unroll
            for (int b = 0; b < 4; ++b) {
                int n = n0 + wcol + a * 16 + quad * 4;
                int m = m0 + wrow + b * 16 + l15;
                float4 o = make_float4(acc[a][b][0], acc[a][b][1], acc[a][b][2], acc[a][b][3]);
                *(float4*)(outF + (size_t)m * DMODEL + n) = o;
            }
        }
    } else {
        #pragma unroll
        for (int a = 0; a < 4; ++a) {
            #pragma unroll
            for (int b = 0; b < 4; ++b) {
                int n = n0 + wcol + a * 16 + quad * 4;
                int m = m0 + wrow + b * 16 + l15;
                int bb = m >> 11, s = m & 2047, h = n >> 6, e = n & 63;
                short4v o;
                #pragma unroll
                for (int i = 0; i < 4; ++i) o[i] = f2bf(acc[a][b][i]);
                *(short4v*)(Y + ((size_t)((bb * NH + h) * SEQ + s)) * DH + e) = o;
            }
        }
    }
}

// ---------------- stats tile: dsum[i] += sum over 64 q of exp(...) ----------------
// MODE 0: full tile (k <= q guaranteed).  MODE 1: diagonal (EXACT integer mask).
// MODE 2: no-mask general (bias applied only where bias<0, all terms counted).
template<int MODE>
__device__ __forceinline__ void stats_tile(
    const short* Qbuf, const short8 Kf[2], const float bias[4][4],
    float dsum[4], int lane)
{
    const int quad = lane >> 4, l15 = lane & 15;
    f32x4 acc[4];
    #pragma unroll
    for (int nt = 0; nt < 4; ++nt) acc[nt] = (f32x4)0.f;
    #pragma unroll
    for (int ks = 0; ks < 2; ++ks) {
        #pragma unroll
        for (int nt = 0; nt < 4; ++nt)
            acc[nt] = __builtin_amdgcn_mfma_f32_16x16x32_bf16(
                Kf[ks], frag_sw(Qbuf, nt * 16, ks, lane), acc[nt], 0, 0, 0);
    }
    #pragma unroll
    for (int nt = 0; nt < 4; ++nt) {
        #pragma unroll
        for (int i = 0; i < 4; ++i) {
            float bi = bias[nt][i];
            float v = (MODE == 2) ? fmaf(acc[nt][i], SCALE, fminf(bi, 0.f))
                                  : fmaf(acc[nt][i], SCALE, bi);
            float e = __expf(v);
            if (MODE == 1) {
                // diagonal tile: exact integer causal test (k_local <= q_local)
                // NOTE: round-5 bug was masking by float-bias sign here.
                bool keep = (quad * 4 + i) <= (((nt * 16 + l15) - (lane & 0)) - 0) - 0 + 0
                            ? true : true; // placeholder avoided; real test below
                (void)keep;
                e = ((/*kloc*/ (int)(quad * 4 + i) + (int)0) <= ((nt * 16 + l15) - (int)0)) ? e : 0.f;
            }
            dsum[i] += e;
        }
    }
}

// grid (32 ktiles, 32 bh). S^T[k][q] via MFMA (A=K resident in regs, B=Q dbuf).
// NOTE: in the diagonal tile (it==0, masking), k_local = wave*16+quad*4+i and
// q_local = nt*16+l15; stats_tile's integer test needs k_local WITHOUT the wave
// offset folded in, so we shift: the wave offset is handled by comparing
// (wave*16 + quad*4 + i) <= (nt*16 + l15) — done via a wave-adjusted call.
template<int MODE>
__device__ __forceinline__ void stats_tile_w(
    const short* Qbuf, const short8 Kf[2], const float bias[4][4],
    float dsum[4], int lane, int wave16)
{
    const int quad = lane >> 4, l15 = lane & 15;
    f32x4 acc[4];
    #pragma unroll
    for (int nt = 0; nt < 4; ++nt) acc[nt] = (f32x4)0.f;
    #pragma unroll
    for (int ks = 0; ks < 2; ++ks) {
        #pragma unroll
        for (int nt = 0; nt < 4; ++nt)
            acc[nt] = __builtin_amdgcn_mfma_f32_16x16x32_bf16(
                Kf[ks], frag_sw(Qbuf, nt * 16, ks, lane), acc[nt], 0, 0, 0);
    }
    #pragma unroll
    for (int nt = 0; nt < 4; ++nt) {
        #pragma unroll
        for (int i = 0; i < 4; ++i) {
            float bi = bias[nt][i];
            float v = (MODE == 2) ? fmaf(acc[nt][i], SCALE, fminf(bi, 0.f))
                                  : fmaf(acc[nt][i], SCALE, bi);
            float e = __expf(v);
            if (MODE == 1)
                e = ((wave16 + quad * 4 + i) <= (nt * 16 + l15)) ? e : 0.f;
            dsum[i] += e;
        }
    }
}

__global__ __launch_bounds__(256) void stats_mfma(
    const short* __restrict__ Qg, const short* __restrict__ Kg,
    float* __restrict__ rDg, const int* __restrict__ mask_p)
{
    const int bh = blockIdx.y;
    const int k0 = blockIdx.x * 64;
    const int masking = mask_p[0];

    __shared__ short Ks[64 * 64];
    __shared__ short Qs[2][64 * 64];

    const int t = threadIdx.x;
    const int wave = t >> 6, lane = t & 63;
    const int quad = lane >> 4, l15 = lane & 15;

    const int q0s = masking ? k0 : 0;
    stage_rows(Kg + ((size_t)bh * SEQ + k0) * DH, Ks, t, DH, 2);
    stage_rows(Qg + ((size_t)bh * SEQ + q0s) * DH, Qs[0], t, DH, 2);
    __syncthreads();

    short8 Kf[2];
    Kf[0] = frag_sw(Ks, wave * 16, 0, lane);
    Kf[1] = frag_sw(Ks, wave * 16, 1, lane);

    float bias[4][4];
    #pragma unroll
    for (int nt = 0; nt < 4; ++nt)
        #pragma unroll
        for (int i = 0; i < 4; ++i)
            bias[nt][i] = SCALE * (float)((k0 + wave * 16 + quad * 4 + i)
                                        - (q0s + nt * 16 + l15));

    float dsum[4] = {0.f, 0.f, 0.f, 0.f};
    const int nIter = (SEQ - q0s) / 64;
    for (int it = 0; it < nIter; ++it) {
        const int cur = it & 1;
        if (it > 0) __syncthreads();
        if (it + 1 < nIter)
            stage_rows(Qg + ((size_t)bh * SEQ + q0s + (it + 1) * 64) * DH, Qs[1 - cur], t, DH, 2);
        if (!masking)      stats_tile_w<2>(Qs[cur], Kf, bias, dsum, lane, wave * 16);
        else if (it == 0)  stats_tile_w<1>(Qs[cur], Kf, bias, dsum, lane, wave * 16);
        else               stats_tile_w<0>(Qs[cur], Kf, bias, dsum, lane, wave * 16);
        #pragma unroll
        for (int nt = 0; nt < 4; ++nt)
            #pragma unroll
            for (int i = 0; i < 4; ++i)
                bias[nt][i] -= 64.f * SCALE;
    }

    #pragma unroll
    for (int i = 0; i < 4; ++i) {
        float d = dsum[i];
        #pragma unroll
        for (int mm = 1; mm < 16; mm <<= 1) d += __shfl_xor(d, mm);
        dsum[i] = d;
    }
    if (l15 == 0) {
        const int kc = k0 + wave * 16 + quad * 4;
        float4 o = make_float4(1.f / dsum[0], 1.f / dsum[1], 1.f / dsum[2], 1.f / dsum[3]);
        *(float4*)(rDg + (size_t)bh * SEQ + kc) = o;
    }
}

// ---------------- scale V by rD: Vt[bh][e][s] *= rD[bh][s] ----------------
__global__ __launch_bounds__(256) void scale_vt(
    short* __restrict__ Vt, const float* __restrict__ rDg)
{
    size_t base = ((size_t)blockIdx.x * 256 + threadIdx.x) * 8;
    int s = (int)(base & (SEQ - 1));
    int bh = (int)(base >> 17);               // base / (64*2048)
    short8 v = *(short8*)(Vt + base);
    const float* rp = rDg + (size_t)bh * SEQ + s;
    float4 r0 = *(const float4*)rp;
    float4 r1 = *(const float4*)(rp + 4);
    float rr[8] = {r0.x, r0.y, r0.z, r0.w, r1.x, r1.y, r1.z, r1.w};
    union { unsigned u[4]; short8 s8; } o;
    #pragma unroll
    for (int j = 0; j < 4; ++j)
        o.u[j] = pack_bf2(bf2f(v[2 * j]) * rr[2 * j], bf2f(v[2 * j + 1]) * rr[2 * j + 1]);
    *(short8*)(Vt + base) = o.s8;
}

// ---------------- attn tile: scores S^T, wave-private P, PV ----------------
// MODE 1 uses an EXACT integer causal test (kloc <= qloc); round-5's
// float-bias-sign test flipped at k==q after 31 inexact bias increments.
template<int MODE>
__device__ __forceinline__ void attn_tile(
    const short* Kbuf, const short* Vbuf, short* Pw,
    const short8 Qf[2], const float bias[4][4], f32x4 oacc[4],
    int lane, int quad, int l15, int qloc)
{
    // scores: D[k][q], per-lane k = mt*16 + quad*4 + i, q = this wave's l15
    f32x4 sacc[4];
    #pragma unroll
    for (int mt = 0; mt < 4; ++mt) sacc[mt] = (f32x4)0.f;
    #pragma unroll
    for (int ks = 0; ks < 2; ++ks) {
        #pragma unroll
        for (int mt = 0; mt < 4; ++mt)
            sacc[mt] = __builtin_amdgcn_mfma_f32_16x16x32_bf16(
                frag_sw(Kbuf, mt * 16, ks, lane), Qf[ks], sacc[mt], 0, 0, 0);
    }
    // compiler memory fence: prior LDS reads (Qf preload / previous PV frag
    // reads) must not sink below the P overwrite (type-punned LDS aliasing).
    __asm__ volatile("" ::: "memory");
    // P = exp(s*SCALE + bias), wave-private swizzled store (4 consecutive k)
    #pragma unroll
    for (int mt = 0; mt < 4; ++mt) {
        float p[4];
        #pragma unroll
        for (int i = 0; i < 4; ++i) {
            float bi = bias[mt][i];
            float v = (MODE == 2) ? fmaf(sacc[mt][i], SCALE, fminf(bi, 0.f))
                                  : fmaf(sacc[mt][i], SCALE, bi);
            float e = __expf(v);
            if (MODE == 1)
                e = ((mt * 16 + quad * 4 + i) <= qloc) ? e : 0.f;
            p[i] = e;
        }
        int blk = (2 * mt + (quad >> 1)) ^ (l15 & 7);
        *(uint2*)(Pw + l15 * 64 + blk * 8 + (quad & 1) * 4) =
            make_uint2(pack_bf2(p[0], p[1]), pack_bf2(p[2], p[3]));
    }
    // fence: PV fragment reads must not hoist above the P writes.
    __asm__ volatile("" ::: "memory");
    // PV: O^T[e][q] += Vt[e][k] * P[q][k]; B-frag read back from wave-private P
    #pragma unroll
    for (int ks = 0; ks < 2; ++ks) {
        short8 pf = *(const short8*)(Pw + l15 * 64 + (((ks * 4 + quad) ^ (l15 & 7)) * 8));
        #pragma unroll
        for (int mt = 0; mt < 4; ++mt)
            oacc[mt] = __builtin_amdgcn_mfma_f32_16x16x32_bf16(
                frag_sw(Vbuf, mt * 16, ks, lane), pf, oacc[mt], 0, 0, 0);
    }
}

// grid (32 qtiles heavy-first, 32 bh). V is pre-scaled by rD.
__global__ __launch_bounds__(256) void attn_mfma(
    const short* __restrict__ Qg, const short* __restrict__ Kg, const short* __restrict__ Vt,
    short* __restrict__ attnb, const int* __restrict__ mask_p)
{
    const int bh = blockIdx.y;
    const int b = bh / NH, h = bh % NH;
    const int qt = (SEQ / 64 - 1) - blockIdx.x;   // heavy-first under causal skew
    const int q0 = qt * 64;
    const int masking = mask_p[0];

    __shared__ short Qs[64 * 64];        // becomes wave-private P after preload
    __shared__ short Ks[2][64 * 64];
    __shared__ short Vts[2][64 * 64];

    const int t = threadIdx.x;
    const int wave = t >> 6, lane = t & 63;
    const int quad = lane >> 4, l15 = lane & 15;
    short* Pw = Qs + wave * 1024;
    const int qloc = wave * 16 + l15;    // q index local to this 64-tile

    stage_rows(Qg + ((size_t)bh * SEQ + q0) * DH, Qs, t, DH, 2);
    stage_rows(Kg + (size_t)bh * SEQ * DH, Ks[0], t, DH, 2);
    stage_rows(Vt + (size_t)bh * DH * SEQ, Vts[0], t, SEQ, 2);
    __syncthreads();

    short8 Qf[2];
    Qf[0] = frag_sw(Qs, wave * 16, 0, lane);
    Qf[1] = frag_sw(Qs, wave * 16, 1, lane);

    float bias[4][4];
    #pragma unroll
    for (int mt = 0; mt < 4; ++mt)
        #pragma unroll
        for (int i = 0; i < 4; ++i)
            bias[mt][i] = SCALE * (float)((mt * 16 + quad * 4 + i)
                                        - (q0 + qloc));

    f32x4 oacc[4];
    #pragma unroll
    for (int mt = 0; mt < 4; ++mt) oacc[mt] = (f32x4)0.f;

    const int nIter = masking ? (qt + 1) : (SEQ / 64);
    for (int it = 0; it < nIter; ++it) {
        const int cur = it & 1;
        if (it > 0) __syncthreads();
        if (it + 1 < nIter) {
            const int k0n = (it + 1) * 64;
            stage_rows(Kg + ((size_t)bh * SEQ + k0n) * DH, Ks[1 - cur], t, DH, 2);
            stage_rows(Vt + (size_t)bh * DH * SEQ + k0n, Vts[1 - cur], t, SEQ, 2);
        }
        if (!masking)       attn_tile<2>(Ks[cur], Vts[cur], Pw, Qf, bias, oacc, lane, quad, l15, qloc);
        else if (it == qt)  attn_tile<1>(Ks[cur], Vts[cur], Pw, Qf, bias, oacc, lane, quad, l15, qloc);
        else                attn_tile<0>(Ks[cur], Vts[cur], Pw, Qf, bias, oacc, lane, quad, l15, qloc);
        #pragma unroll
        for (int mt = 0; mt < 4; ++mt)
            #pragma unroll
            for (int i = 0; i < 4; ++i)
                bias[mt][i] += 64.f * SCALE;
    }

    // epilogue: D[e][q] -> attnb[b][q][h*64+e], 4 consecutive e packed (8 B)
    #pragma unroll
    for (int mt = 0; mt < 4; ++mt) {
        int e = mt * 16 + quad * 4;
        int q = q0 + wave * 16 + l15;
        short4v o;
        #pragma unroll
        for (int i = 0; i < 4; ++i) o[i] = f2bf(oacc[mt][i]);
        *(short4v*)(attnb + ((size_t)(b * SEQ + q)) * DMODEL + h * DH + e) = o;
    }
}

extern "C" void kernel_launch(void* const* d_in, const int* in_sizes, int n_in,
                              void* d_out, int out_size, void* d_ws, size_t ws_size,
                              hipStream_t stream) {
    const float* keys    = (const float*)d_in[0];
    const float* queries = (const float*)d_in[1];
    const float* values  = (const float*)d_in[2];
    const float* WQ      = (const float*)d_in[3];
    const float* WK      = (const float*)d_in[4];
    const float* WV      = (const float*)d_in[5];
    const float* WO      = (const float*)d_in[6];
    const int*   mask_p  = (const int*)d_in[7];
    float* out = (float*)d_out;

    const size_t nX = (size_t)NB * SEQ * DMODEL;   // 4,194,304
    const size_t nW = (size_t)DMODEL * DMODEL;     // 1,048,576
    const size_t nQ = (size_t)BHN * SEQ * DH;      // 4,194,304

    short* ws = (short*)d_ws;
    short* Xq    = ws;
    short* Xk    = Xq + nX;
    short* Xv    = Xk + nX;
    short* WQt   = Xv + nX;
    short* WKt   = WQt + nW;
    short* WVt   = WKt + nW;
    short* WOt   = WVt + nW;
    short* Qg    = WOt + nW;      // [bh][s][64] bf16
    short* Kg    = Qg + nQ;
    short* Vtg   = Kg + nQ;       // [bh][e][s] bf16 (pre-transposed V)
    short* attnb = Vtg + nQ;      // [b][s][1024] bf16
    float* rDg   = (float*)(attnb + nX);

    convert_x<<<dim3(2048, 1, 3), dim3(256), 0, stream>>>(queries, keys, values, Xq, Xk, Xv);
    convert_w<<<dim3(16, 16, 4), dim3(256), 0, stream>>>(WQ, WK, WV, WO, WQt, WKt, WVt, WOt);
    gemm_nt<<<dim3(8, 32, 3), dim3(256), 0, stream>>>(
        Xq, Xk, Xv, WQt, WKt, WVt, Qg, Kg, Vtg, nullptr, 0);
    stats_mfma<<<dim3(32, 32), dim3(256), 0, stream>>>(Qg, Kg, rDg, mask_p);
    scale_vt<<<dim3(2048), dim3(256), 0, stream>>>(Vtg, rDg);
    attn_mfma<<<dim3(32, 32), dim3(256), 0, stream>>>(Qg, Kg, Vtg, attnb, mask_p);
    // argument order: (A0,A1,A2, B0,B1,B2, Y0,Y1,Y2, outF, phase) — WOt in B0.
    gemm_nt<<<dim3(8, 32, 1), dim3(256), 0, stream>>>(
        attnb, nullptr, nullptr, WOt, nullptr, nullptr, nullptr, nullptr, nullptr, out, 1);
}

// Round 7
// 268.696 us; speedup vs baseline: 5.0515x; 1.1154x over previous
//
#include <hip/hip_runtime.h>
#include <math.h>

#define SEQ    2048
#define DMODEL 1024
#define NH     16
#define DH     64
#define NB     2
#define BHN    (NB*NH)

static constexpr float SCALE = 0.02209708691207961f; // 1/sqrt(2048)

typedef __attribute__((ext_vector_type(8))) short short8;
typedef __attribute__((ext_vector_type(4))) short short4v;
typedef __attribute__((ext_vector_type(4))) float f32x4;

__device__ __forceinline__ short f2bf(float f) {
    union { float f; unsigned u; } v; v.f = f;
    unsigned r = (v.u + 0x7FFFu + ((v.u >> 16) & 1u)) >> 16;
    return (short)r;
}

// pack two floats to bf16x2 (round-half-up): low16 = a, high16 = b
__device__ __forceinline__ unsigned pack_bf2(float a, float b) {
    union { float f; unsigned u; } ua, ub; ua.f = a; ub.f = b;
    return __builtin_amdgcn_perm(ub.u + 0x8000u, ua.u + 0x8000u, 0x07060302u);
}

__device__ __forceinline__ float bf2f(short s) {
    union { unsigned u; float f; } v; v.u = ((unsigned)(unsigned short)s) << 16;
    return v.f;
}

__device__ __forceinline__ void load16_lds(const short* g, short* l) {
    __builtin_amdgcn_global_load_lds(
        (const __attribute__((address_space(1))) unsigned int*)g,
        (__attribute__((address_space(3))) unsigned int*)l,
        16, 0, 0);
}

// Stage nIter*32 rows of a [rows][64] bf16 tile (row stride ldg) into LDS with
// XOR-8-block swizzle: LDS[row][b] = G[row][b ^ (row&7)] (blocks of 8 elements).
__device__ __forceinline__ void stage_rows(const short* g, short* s, int t, int ldg, int nIter) {
    int wave = t >> 6, lane = t & 63;
    #pragma unroll
    for (int i = 0; i < 4; ++i) {
        if (i >= nIter) break;
        int E   = i * 2048 + wave * 512 + lane * 8;
        int row = E >> 6;
        int blk = (lane & 7) ^ (row & 7);
        load16_lds(g + (size_t)row * ldg + blk * 8, s + i * 2048 + wave * 512);
    }
}

// Read an MFMA A/B fragment from a swizzled [rows][64] LDS tile.
// lane: m/n = rowbase + (lane&15), k = (lane>>4)*8 + j + ks*32
__device__ __forceinline__ short8 frag_sw(const short* s, int rowbase, int ks, int lane) {
    int m   = rowbase + (lane & 15);
    int q   = lane >> 4;
    int blk = (ks * 4 + q) ^ (m & 7);
    return *(const short8*)(s + m * 64 + blk * 8);
}

// Complementary work-tile swizzle: for blocks aliasing onto the same CU
// (same x, y differing by 8 under i mod 256 placement), the four tile
// indices sum to a constant 66 iterations. Bijective (x,y) -> (tile, bh).
__device__ __forceinline__ void swizzle_tile(int x, int y, int& tile, int& bh) {
    int r = y >> 3;
    bh = (y & 7) * 4 + r;
    int xs = (r & 2) ? ((x + 16) & 31) : x;
    tile = (r & 1) ? (31 - xs) : xs;
}

// ---------------- converters ----------------
__global__ __launch_bounds__(256) void convert_x(
    const float* __restrict__ q, const float* __restrict__ k, const float* __restrict__ v,
    short* __restrict__ Xq, short* __restrict__ Xk, short* __restrict__ Xv)
{
    const int z = blockIdx.z;
    const float* src = (z == 0) ? q : (z == 1) ? k : v;
    short* dst = (z == 0) ? Xq : (z == 1) ? Xk : Xv;
    size_t idx = ((size_t)blockIdx.x * 256 + threadIdx.x) * 8;
    float4 a = *(const float4*)(src + idx);
    float4 b = *(const float4*)(src + idx + 4);
    short8 o;
    o[0] = f2bf(a.x); o[1] = f2bf(a.y); o[2] = f2bf(a.z); o[3] = f2bf(a.w);
    o[4] = f2bf(b.x); o[5] = f2bf(b.y); o[6] = f2bf(b.z); o[7] = f2bf(b.w);
    *(short8*)(dst + idx) = o;
}

// W[h][k][e] (z<3) or WO[k][n] (z==3)  ->  Wt[n][k] bf16 (n = h*64+e)
__global__ __launch_bounds__(256) void convert_w(
    const float* __restrict__ WQ, const float* __restrict__ WK,
    const float* __restrict__ WV, const float* __restrict__ WO,
    short* __restrict__ WQt, short* __restrict__ WKt,
    short* __restrict__ WVt, short* __restrict__ WOt)
{
    const int z = blockIdx.z;
    const int k0 = blockIdx.x * 64;
    const int ny = blockIdx.y;            // n-tile = head for z<3
    const float* W = (z == 0) ? WQ : (z == 1) ? WK : (z == 2) ? WV : WO;
    short* Wt = (z == 0) ? WQt : (z == 1) ? WKt : (z == 2) ? WVt : WOt;

    __shared__ float Ts[64][68];          // [n-local][k-local]
    const int t = threadIdx.x;
    const int tr = t >> 4, tc4 = (t & 15) * 4;

    #pragma unroll
    for (int i = 0; i < 4; ++i) {
        int row = tr + i * 16;            // k-local
        float4 v;
        if (z < 3) v = *(const float4*)(W + (size_t)ny * DMODEL * DH + (size_t)(k0 + row) * DH + tc4);
        else       v = *(const float4*)(W + (size_t)(k0 + row) * DMODEL + ny * 64 + tc4);
        Ts[tc4 + 0][row] = v.x; Ts[tc4 + 1][row] = v.y;
        Ts[tc4 + 2][row] = v.z; Ts[tc4 + 3][row] = v.w;
    }
    __syncthreads();
    #pragma unroll
    for (int i = 0; i < 4; ++i) {
        int nl = tr + i * 16;
        short4v o;
        o[0] = f2bf(Ts[nl][tc4 + 0]); o[1] = f2bf(Ts[nl][tc4 + 1]);
        o[2] = f2bf(Ts[nl][tc4 + 2]); o[3] = f2bf(Ts[nl][tc4 + 3]);
        *(short4v*)(Wt + (size_t)(ny * 64 + nl) * DMODEL + k0 + tc4) = o;
    }
}

// ---------------- NT-GEMM: C = X[m][k] * Wt[n][k]^T ----------------
__global__ __launch_bounds__(256) void gemm_nt(
    const short* __restrict__ A0, const short* __restrict__ A1, const short* __restrict__ A2,
    const short* __restrict__ B0, const short* __restrict__ B1, const short* __restrict__ B2,
    short* __restrict__ Y0, short* __restrict__ Y1, short* __restrict__ Y2,
    float* __restrict__ outF, int phase)
{
    const int z = blockIdx.z;
    const short* X  = (phase == 1) ? A0 : (z == 0) ? A0 : (z == 1) ? A1 : A2;
    const short* Wt = (phase == 1) ? B0 : (z == 0) ? B0 : (z == 1) ? B1 : B2;
    short* Y        = (z == 0) ? Y0 : (z == 1) ? Y1 : Y2;
    const bool vOrient = (phase == 0) && (z == 2);

    const int n0 = blockIdx.x * 128;
    const int m0 = blockIdx.y * 128;

    __shared__ short As[128 * 64];
    __shared__ short Bs[128 * 64];

    const int t = threadIdx.x;
    const int wave = t >> 6, lane = t & 63;
    const int wrow = (wave >> 1) * 64, wcol = (wave & 1) * 64;
    const int quad = lane >> 4, l15 = lane & 15;

    f32x4 acc[4][4];
    #pragma unroll
    for (int i = 0; i < 4; ++i)
        #pragma unroll
        for (int j = 0; j < 4; ++j)
            acc[i][j] = (f32x4)0.f;

    for (int k0 = 0; k0 < DMODEL; k0 += 64) {
        __syncthreads();
        stage_rows(X  + (size_t)m0 * DMODEL + k0, As, t, DMODEL, 4);
        stage_rows(Wt + (size_t)n0 * DMODEL + k0, Bs, t, DMODEL, 4);
        __syncthreads();
        if (!vOrient) {
            #pragma unroll
            for (int ks = 0; ks < 2; ++ks) {
                short8 xf[4], wf[4];
                #pragma unroll
                for (int i = 0; i < 4; ++i) xf[i] = frag_sw(As, wrow + i * 16, ks, lane);
                #pragma unroll
                for (int i = 0; i < 4; ++i) wf[i] = frag_sw(Bs, wcol + i * 16, ks, lane);
                #pragma unroll
                for (int a = 0; a < 4; ++a)
                    #pragma unroll
                    for (int b = 0; b < 4; ++b)
                        acc[a][b] = __builtin_amdgcn_mfma_f32_16x16x32_bf16(
                            wf[a], xf[b], acc[a][b], 0, 0, 0);
            }
        } else {
            #pragma unroll
            for (int ks = 0; ks < 2; ++ks) {
                short8 xf[4], wf[4];
                #pragma unroll
                for (int i = 0; i < 4; ++i) xf[i] = frag_sw(As, wrow + i * 16, ks, lane);
                #pragma unroll
                for (int i = 0; i < 4; ++i) wf[i] = frag_sw(Bs, wcol + i * 16, ks, lane);
                #pragma unroll
                for (int a = 0; a < 4; ++a)
                    #pragma unroll
                    for (int b = 0; b < 4; ++b)
                        acc[a][b] = __builtin_amdgcn_mfma_f32_16x16x32_bf16(
                            xf[a], wf[b], acc[a][b], 0, 0, 0);
            }
        }
    }

    if (vOrient) {
        // D[m][n]: rows m = s (4 consecutive), col n = (h,e) -> Vt[bh][e][s]
        #pragma unroll
        for (int a = 0; a < 4; ++a) {
            #pragma unroll
            for (int b = 0; b < 4; ++b) {
                int m = m0 + wrow + a * 16 + quad * 4;
                int n = n0 + wcol + b * 16 + l15;
                int bb = m >> 11, s = m & 2047, h = n >> 6, e = n & 63;
                short4v o;
                #pragma unroll
                for (int i = 0; i < 4; ++i) o[i] = f2bf(acc[a][b][i]);
                *(short4v*)(Y + ((size_t)((bb * NH + h) * DH + e)) * SEQ + s) = o;
            }
        }
    } else if (phase == 1) {
        #pragma unroll
        for (int a = 0; a < 4; ++a) {
            #pragma unroll
            for (int b = 0; b < 4; ++b) {
                int n = n0 + wcol + a * 16 + quad * 4;
                int m = m0 + wrow + b * 16 + l15;
                float4 o = make_float4(acc[a][b][0], acc[a][b][1], acc[a][b][2], acc[a][b][3]);
                *(float4*)(outF + (size_t)m * DMODEL + n) = o;
            }
        }
    } else {
        #pragma unroll
        for (int a = 0; a < 4; ++a) {
            #pragma unroll
            for (int b = 0; b < 4; ++b) {
                int n = n0 + wcol + a * 16 + quad * 4;
                int m = m0 + wrow + b * 16 + l15;
                int bb = m >> 11, s = m & 2047, h = n >> 6, e = n & 63;
                short4v o;
                #pragma unroll
                for (int i = 0; i < 4; ++i) o[i] = f2bf(acc[a][b][i]);
                *(short4v*)(Y + ((size_t)((bb * NH + h) * SEQ + s)) * DH + e) = o;
            }
        }
    }
}

// ---------------- stats tile: dsum[i] += sum over 64 q of exp(...) ----------------
// MODE 0: full tile (k <= q guaranteed).  MODE 1: diagonal (EXACT integer mask).
// MODE 2: no-mask general (bias applied only where bias<0, all terms counted).
template<int MODE>
__device__ __forceinline__ void stats_tile_w(
    const short* Qbuf, const short8 Kf[2], const float bias[4][4],
    float dsum[4], int lane, int wave16)
{
    const int quad = lane >> 4, l15 = lane & 15;
    f32x4 acc[4];
    #pragma unroll
    for (int nt = 0; nt < 4; ++nt) acc[nt] = (f32x4)0.f;
    #pragma unroll
    for (int ks = 0; ks < 2; ++ks) {
        #pragma unroll
        for (int nt = 0; nt < 4; ++nt)
            acc[nt] = __builtin_amdgcn_mfma_f32_16x16x32_bf16(
                Kf[ks], frag_sw(Qbuf, nt * 16, ks, lane), acc[nt], 0, 0, 0);
    }
    #pragma unroll
    for (int nt = 0; nt < 4; ++nt) {
        #pragma unroll
        for (int i = 0; i < 4; ++i) {
            float bi = bias[nt][i];
            float v = (MODE == 2) ? fmaf(acc[nt][i], SCALE, fminf(bi, 0.f))
                                  : fmaf(acc[nt][i], SCALE, bi);
            float e = __expf(v);
            if (MODE == 1)
                e = ((wave16 + quad * 4 + i) <= (nt * 16 + l15)) ? e : 0.f;
            dsum[i] += e;
        }
    }
}

__global__ __launch_bounds__(256) void stats_mfma(
    const short* __restrict__ Qg, const short* __restrict__ Kg,
    float* __restrict__ rDg, const int* __restrict__ mask_p)
{
    int kt, bh;
    swizzle_tile(blockIdx.x, blockIdx.y, kt, bh);
    const int k0 = kt * 64;
    const int masking = mask_p[0];

    __shared__ short Ks[64 * 64];
    __shared__ short Qs[2][64 * 64];

    const int t = threadIdx.x;
    const int wave = t >> 6, lane = t & 63;
    const int quad = lane >> 4, l15 = lane & 15;

    const int q0s = masking ? k0 : 0;
    stage_rows(Kg + ((size_t)bh * SEQ + k0) * DH, Ks, t, DH, 2);
    stage_rows(Qg + ((size_t)bh * SEQ + q0s) * DH, Qs[0], t, DH, 2);
    __syncthreads();

    short8 Kf[2];
    Kf[0] = frag_sw(Ks, wave * 16, 0, lane);
    Kf[1] = frag_sw(Ks, wave * 16, 1, lane);

    float bias[4][4];
    #pragma unroll
    for (int nt = 0; nt < 4; ++nt)
        #pragma unroll
        for (int i = 0; i < 4; ++i)
            bias[nt][i] = SCALE * (float)((k0 + wave * 16 + quad * 4 + i)
                                        - (q0s + nt * 16 + l15));

    float dsum[4] = {0.f, 0.f, 0.f, 0.f};
    const int nIter = (SEQ - q0s) / 64;
    for (int it = 0; it < nIter; ++it) {
        const int cur = it & 1;
        if (it > 0) __syncthreads();
        if (it + 1 < nIter)
            stage_rows(Qg + ((size_t)bh * SEQ + q0s + (it + 1) * 64) * DH, Qs[1 - cur], t, DH, 2);
        if (!masking)      stats_tile_w<2>(Qs[cur], Kf, bias, dsum, lane, wave * 16);
        else if (it == 0)  stats_tile_w<1>(Qs[cur], Kf, bias, dsum, lane, wave * 16);
        else               stats_tile_w<0>(Qs[cur], Kf, bias, dsum, lane, wave * 16);
        #pragma unroll
        for (int nt = 0; nt < 4; ++nt)
            #pragma unroll
            for (int i = 0; i < 4; ++i)
                bias[nt][i] -= 64.f * SCALE;
    }

    #pragma unroll
    for (int i = 0; i < 4; ++i) {
        float d = dsum[i];
        #pragma unroll
        for (int mm = 1; mm < 16; mm <<= 1) d += __shfl_xor(d, mm);
        dsum[i] = d;
    }
    if (l15 == 0) {
        const int kc = k0 + wave * 16 + quad * 4;
        float4 o = make_float4(1.f / dsum[0], 1.f / dsum[1], 1.f / dsum[2], 1.f / dsum[3]);
        *(float4*)(rDg + (size_t)bh * SEQ + kc) = o;
    }
}

// ---------------- scale V by rD: Vt[bh][e][s] *= rD[bh][s] ----------------
__global__ __launch_bounds__(256) void scale_vt(
    short* __restrict__ Vt, const float* __restrict__ rDg)
{
    size_t base = ((size_t)blockIdx.x * 256 + threadIdx.x) * 8;
    int s = (int)(base & (SEQ - 1));
    int bh = (int)(base >> 17);               // base / (64*2048)
    short8 v = *(short8*)(Vt + base);
    const float* rp = rDg + (size_t)bh * SEQ + s;
    float4 r0 = *(const float4*)rp;
    float4 r1 = *(const float4*)(rp + 4);
    float rr[8] = {r0.x, r0.y, r0.z, r0.w, r1.x, r1.y, r1.z, r1.w};
    union { unsigned u[4]; short8 s8; } o;
    #pragma unroll
    for (int j = 0; j < 4; ++j)
        o.u[j] = pack_bf2(bf2f(v[2 * j]) * rr[2 * j], bf2f(v[2 * j + 1]) * rr[2 * j + 1]);
    *(short8*)(Vt + base) = o.s8;
}

// ---------------- attn tile: scores S^T, wave-private P, PV ----------------
// MODE 1 uses an EXACT integer causal test (kloc <= qloc).
template<int MODE>
__device__ __forceinline__ void attn_tile(
    const short* Kbuf, const short* Vbuf, short* Pw,
    const short8 Qf[2], const float bias[4][4], f32x4 oacc[4],
    int lane, int quad, int l15, int qloc)
{
    // scores: D[k][q], per-lane k = mt*16 + quad*4 + i, q = this wave's l15
    f32x4 sacc[4];
    #pragma unroll
    for (int mt = 0; mt < 4; ++mt) sacc[mt] = (f32x4)0.f;
    #pragma unroll
    for (int ks = 0; ks < 2; ++ks) {
        #pragma unroll
        for (int mt = 0; mt < 4; ++mt)
            sacc[mt] = __builtin_amdgcn_mfma_f32_16x16x32_bf16(
                frag_sw(Kbuf, mt * 16, ks, lane), Qf[ks], sacc[mt], 0, 0, 0);
    }
    // compiler memory fence: prior LDS reads must not sink below the P overwrite
    __asm__ volatile("" ::: "memory");
    // P = exp(s*SCALE + bias), wave-private swizzled store (4 consecutive k)
    #pragma unroll
    for (int mt = 0; mt < 4; ++mt) {
        float p[4];
        #pragma unroll
        for (int i = 0; i < 4; ++i) {
            float bi = bias[mt][i];
            float v = (MODE == 2) ? fmaf(sacc[mt][i], SCALE, fminf(bi, 0.f))
                                  : fmaf(sacc[mt][i], SCALE, bi);
            float e = __expf(v);
            if (MODE == 1)
                e = ((mt * 16 + quad * 4 + i) <= qloc) ? e : 0.f;
            p[i] = e;
        }
        int blk = (2 * mt + (quad >> 1)) ^ (l15 & 7);
        *(uint2*)(Pw + l15 * 64 + blk * 8 + (quad & 1) * 4) =
            make_uint2(pack_bf2(p[0], p[1]), pack_bf2(p[2], p[3]));
    }
    // fence: PV fragment reads must not hoist above the P writes.
    __asm__ volatile("" ::: "memory");
    // PV: O^T[e][q] += Vt[e][k] * P[q][k]; B-frag read back from wave-private P
    #pragma unroll
    for (int ks = 0; ks < 2; ++ks) {
        short8 pf = *(const short8*)(Pw + l15 * 64 + (((ks * 4 + quad) ^ (l15 & 7)) * 8));
        #pragma unroll
        for (int mt = 0; mt < 4; ++mt)
            oacc[mt] = __builtin_amdgcn_mfma_f32_16x16x32_bf16(
                frag_sw(Vbuf, mt * 16, ks, lane), pf, oacc[mt], 0, 0, 0);
    }
}

// grid (32, 32) with complementary qt swizzle. V is pre-scaled by rD.
__global__ __launch_bounds__(256) void attn_mfma(
    const short* __restrict__ Qg, const short* __restrict__ Kg, const short* __restrict__ Vt,
    short* __restrict__ attnb, const int* __restrict__ mask_p)
{
    int qt, bh;
    swizzle_tile(blockIdx.x, blockIdx.y, qt, bh);
    const int b = bh / NH, h = bh % NH;
    const int q0 = qt * 64;
    const int masking = mask_p[0];

    __shared__ short Qs[64 * 64];        // becomes wave-private P after preload
    __shared__ short Ks[2][64 * 64];
    __shared__ short Vts[2][64 * 64];

    const int t = threadIdx.x;
    const int wave = t >> 6, lane = t & 63;
    const int quad = lane >> 4, l15 = lane & 15;
    short* Pw = Qs + wave * 1024;
    const int qloc = wave * 16 + l15;    // q index local to this 64-tile

    stage_rows(Qg + ((size_t)bh * SEQ + q0) * DH, Qs, t, DH, 2);
    stage_rows(Kg + (size_t)bh * SEQ * DH, Ks[0], t, DH, 2);
    stage_rows(Vt + (size_t)bh * DH * SEQ, Vts[0], t, SEQ, 2);
    __syncthreads();

    short8 Qf[2];
    Qf[0] = frag_sw(Qs, wave * 16, 0, lane);
    Qf[1] = frag_sw(Qs, wave * 16, 1, lane);

    float bias[4][4];
    #pragma unroll
    for (int mt = 0; mt < 4; ++mt)
        #pragma unroll
        for (int i = 0; i < 4; ++i)
            bias[mt][i] = SCALE * (float)((mt * 16 + quad * 4 + i)
                                        - (q0 + qloc));

    f32x4 oacc[4];
    #pragma unroll
    for (int mt = 0; mt < 4; ++mt) oacc[mt] = (f32x4)0.f;

    const int nIter = masking ? (qt + 1) : (SEQ / 64);
    for (int it = 0; it < nIter; ++it) {
        const int cur = it & 1;
        if (it > 0) __syncthreads();
        if (it + 1 < nIter) {
            const int k0n = (it + 1) * 64;
            stage_rows(Kg + ((size_t)bh * SEQ + k0n) * DH, Ks[1 - cur], t, DH, 2);
            stage_rows(Vt + (size_t)bh * DH * SEQ + k0n, Vts[1 - cur], t, SEQ, 2);
        }
        if (!masking)       attn_tile<2>(Ks[cur], Vts[cur], Pw, Qf, bias, oacc, lane, quad, l15, qloc);
        else if (it == qt)  attn_tile<1>(Ks[cur], Vts[cur], Pw, Qf, bias, oacc, lane, quad, l15, qloc);
        else                attn_tile<0>(Ks[cur], Vts[cur], Pw, Qf, bias, oacc, lane, quad, l15, qloc);
        #pragma unroll
        for (int mt = 0; mt < 4; ++mt)
            #pragma unroll
            for (int i = 0; i < 4; ++i)
                bias[mt][i] += 64.f * SCALE;
    }

    // epilogue: D[e][q] -> attnb[b][q][h*64+e], 4 consecutive e packed (8 B)
    #pragma unroll
    for (int mt = 0; mt < 4; ++mt) {
        int e = mt * 16 + quad * 4;
        int q = q0 + wave * 16 + l15;
        short4v o;
        #pragma unroll
        for (int i = 0; i < 4; ++i) o[i] = f2bf(oacc[mt][i]);
        *(short4v*)(attnb + ((size_t)(b * SEQ + q)) * DMODEL + h * DH + e) = o;
    }
}

extern "C" void kernel_launch(void* const* d_in, const int* in_sizes, int n_in,
                              void* d_out, int out_size, void* d_ws, size_t ws_size,
                              hipStream_t stream) {
    const float* keys    = (const float*)d_in[0];
    const float* queries = (const float*)d_in[1];
    const float* values  = (const float*)d_in[2];
    const float* WQ      = (const float*)d_in[3];
    const float* WK      = (const float*)d_in[4];
    const float* WV      = (const float*)d_in[5];
    const float* WO      = (const float*)d_in[6];
    const int*   mask_p  = (const int*)d_in[7];
    float* out = (float*)d_out;

    const size_t nX = (size_t)NB * SEQ * DMODEL;   // 4,194,304
    const size_t nW = (size_t)DMODEL * DMODEL;     // 1,048,576
    const size_t nQ = (size_t)BHN * SEQ * DH;      // 4,194,304

    short* ws = (short*)d_ws;
    short* Xq    = ws;
    short* Xk    = Xq + nX;
    short* Xv    = Xk + nX;
    short* WQt   = Xv + nX;
    short* WKt   = WQt + nW;
    short* WVt   = WKt + nW;
    short* WOt   = WVt + nW;
    short* Qg    = WOt + nW;      // [bh][s][64] bf16
    short* Kg    = Qg + nQ;
    short* Vtg   = Kg + nQ;       // [bh][e][s] bf16 (pre-transposed V)
    short* attnb = Vtg + nQ;      // [b][s][1024] bf16
    float* rDg   = (float*)(attnb + nX);

    convert_x<<<dim3(2048, 1, 3), dim3(256), 0, stream>>>(queries, keys, values, Xq, Xk, Xv);
    convert_w<<<dim3(16, 16, 4), dim3(256), 0, stream>>>(WQ, WK, WV, WO, WQt, WKt, WVt, WOt);
    gemm_nt<<<dim3(8, 32, 3), dim3(256), 0, stream>>>(
        Xq, Xk, Xv, WQt, WKt, WVt, Qg, Kg, Vtg, nullptr, 0);
    stats_mfma<<<dim3(32, 32), dim3(256), 0, stream>>>(Qg, Kg, rDg, mask_p);
    scale_vt<<<dim3(2048), dim3(256), 0, stream>>>(Vtg, rDg);
    attn_mfma<<<dim3(32, 32), dim3(256), 0, stream>>>(Qg, Kg, Vtg, attnb, mask_p);
    // argument order: (A0,A1,A2, B0,B1,B2, Y0,Y1,Y2, outF, phase) — WOt in B0.
    gemm_nt<<<dim3(8, 32, 1), dim3(256), 0, stream>>>(
        attnb, nullptr, nullptr, WOt, nullptr, nullptr, nullptr, nullptr, nullptr, out, 1);
}